// Round 4
// baseline (13332.681 us; speedup 1.0000x reference)
//
#include <hip/hip_runtime.h>
#include <math.h>

#define NN 100000
#define NE 1600000
#define DD 64
#define NL 4
#define NH 4
#define NC 16
#define DIN 192
#define SLOPE 0.2f

typedef __bf16 bf8 __attribute__((ext_vector_type(8)));
typedef __bf16 bf4 __attribute__((ext_vector_type(4)));
typedef float f32x4 __attribute__((ext_vector_type(4)));

__device__ __forceinline__ f32x4 MFMA(bf8 a, bf8 b, f32x4 c) {
  return __builtin_amdgcn_mfma_f32_16x16x32_bf16(a, b, c, 0, 0, 0);
}

__device__ __forceinline__ float atomicMaxF(float* addr, float val) {
  if (val >= 0.f) return __int_as_float(atomicMax((int*)addr, __float_as_int(val)));
  return __uint_as_float(atomicMin((unsigned int*)addr, __float_as_uint(val)));
}

// ---------------- weight packing into MFMA B-fragment layout ----------------
// per (t,s) tile: 64 lanes x [8 bf16 hi | 8 bf16 lo] (32B/lane)
// element j of lane l = W[k][n], k = s*32 + (l>>4)*8 + j, n = t*16 + (l&15)
__global__ void k_pack_w1(const float* __restrict__ W1, __bf16* __restrict__ W1P) {
  int gidx = blockIdx.x * 256 + threadIdx.x;
  if (gidx >= 4 * 4608) return;
  int lyr = gidx / 4608, rem = gidx % 4608;
  int lane = rem & 63, ts = rem >> 6;
  int s = ts % 6, t = ts / 6;
  const float* Wl = W1 + (size_t)lyr * DIN * DIN;
  __bf16* out = W1P + (size_t)lyr * 73728 + ((size_t)(t * 6 + s) * 64 + lane) * 16;
  int k0 = s * 32 + (lane >> 4) * 8, n = t * 16 + (lane & 15);
#pragma unroll
  for (int j = 0; j < 8; ++j) {
    float v = Wl[(size_t)(k0 + j) * DIN + n];
    __bf16 h = (__bf16)v;
    out[j] = h;
    out[8 + j] = (__bf16)(v - (float)h);
  }
}

__global__ void k_pack_w2(const float* __restrict__ W2, __bf16* __restrict__ W2P) {
  int gidx = blockIdx.x * 256 + threadIdx.x;
  if (gidx >= 4 * 1536) return;
  int lyr = gidx / 1536, rem = gidx % 1536;
  int lane = rem & 63, ts = rem >> 6;
  int s = ts % 6, t = ts / 6;
  const float* Wl = W2 + (size_t)lyr * DIN * DD;
  __bf16* out = W2P + (size_t)lyr * 24576 + ((size_t)(t * 6 + s) * 64 + lane) * 16;
  int k0 = s * 32 + (lane >> 4) * 8, n = t * 16 + (lane & 15);
#pragma unroll
  for (int j = 0; j < 8; ++j) {
    float v = Wl[(size_t)(k0 + j) * DD + n];
    __bf16 h = (__bf16)v;
    out[j] = h;
    out[8 + j] = (__bf16)(v - (float)h);
  }
}

// ---------------- GAT conv path ----------------
__global__ void k_compute_v(const float* __restrict__ ew, const float* __restrict__ ae,
                            float* __restrict__ v) {
  int d = threadIdx.x >> 2, h = threadIdx.x & 3;
  float s = 0.f;
#pragma unroll
  for (int c = 0; c < NC; ++c) s = fmaf(ew[d * DD + h * NC + c], ae[h * NC + c], s);
  v[d * NH + h] = s;
}

__global__ void k_xh(const float* __restrict__ nf, const float* __restrict__ W,
                     const float* __restrict__ as_, const float* __restrict__ ad_,
                     float* __restrict__ xh, float* __restrict__ asrc,
                     float* __restrict__ adst) {
  int t = blockIdx.x * 4 + (threadIdx.x >> 6);
  int d = threadIdx.x & 63;
  if (t >= NN) return;
  const float* x = nf + t * DD;
  float acc = 0.f;
#pragma unroll
  for (int k = 0; k < DD; ++k) acc = fmaf(x[k], W[k * DD + d], acc);
  xh[t * DD + d] = acc;
  int h = d >> 4, c = d & 15;
  float ps = acc * as_[h * NC + c];
  float pd = acc * ad_[h * NC + c];
#pragma unroll
  for (int off = 8; off >= 1; off >>= 1) {
    ps += __shfl_xor(ps, off, 64);
    pd += __shfl_xor(pd, off, 64);
  }
  if (c == 0) { asrc[t * NH + h] = ps; adst[t * NH + h] = pd; }
}

__global__ void k_fill(float* __restrict__ accum, float* __restrict__ amax,
                       float* __restrict__ asum) {
  int i = blockIdx.x * 256 + threadIdx.x;
  if (i < NN * DD) accum[i] = 0.f;
  if (i < NN * NH) { amax[i] = -INFINITY; asum[i] = 0.f; }
}

// pass1: 4 lanes per entry; 64 entries per 256-thread block
__global__ void k_pass1(const float* __restrict__ ef, const int* __restrict__ src,
                        const int* __restrict__ dst, const float* __restrict__ v,
                        const float* __restrict__ asrc, const float* __restrict__ adst,
                        float* __restrict__ araw, float* __restrict__ amax) {
  int e = blockIdx.x * 64 + (threadIdx.x >> 2);
  int part = threadIdx.x & 3;
  if (e >= NE + NN) return;
  int s, t;
  float ph0 = 0.f, ph1 = 0.f, ph2 = 0.f, ph3 = 0.f;
  if (e < NE) {
    s = src[e]; t = dst[e];
    const float4* ep = (const float4*)(ef + (size_t)e * DD + part * 16);
    const float4* v4 = (const float4*)v;
#pragma unroll
    for (int c4 = 0; c4 < 4; ++c4) {
      float4 x = ep[c4];
      int d0 = part * 16 + c4 * 4;
      float4 va = v4[d0], vb = v4[d0 + 1], vc = v4[d0 + 2], vd = v4[d0 + 3];
      ph0 = fmaf(x.x, va.x, fmaf(x.y, vb.x, fmaf(x.z, vc.x, fmaf(x.w, vd.x, ph0))));
      ph1 = fmaf(x.x, va.y, fmaf(x.y, vb.y, fmaf(x.z, vc.y, fmaf(x.w, vd.y, ph1))));
      ph2 = fmaf(x.x, va.z, fmaf(x.y, vb.z, fmaf(x.z, vc.z, fmaf(x.w, vd.z, ph2))));
      ph3 = fmaf(x.x, va.w, fmaf(x.y, vb.w, fmaf(x.z, vc.w, fmaf(x.w, vd.w, ph3))));
    }
#pragma unroll
    for (int off = 1; off <= 2; off <<= 1) {
      ph0 += __shfl_xor(ph0, off, 64);
      ph1 += __shfl_xor(ph1, off, 64);
      ph2 += __shfl_xor(ph2, off, 64);
      ph3 += __shfl_xor(ph3, off, 64);
    }
  } else {
    s = t = e - NE;
  }
  float pe = (part == 0) ? ph0 : (part == 1) ? ph1 : (part == 2) ? ph2 : ph3;
  float a = asrc[s * NH + part] + adst[t * NH + part] + pe;
  a = (a > 0.f) ? a : SLOPE * a;
  araw[(size_t)e * NH + part] = a;
  atomicMaxF(&amax[t * NH + part], a);
}

// pass2: 16 lanes per entry (float4 over d); 16 entries per block
__global__ void k_pass2(const float* __restrict__ xh, const int* __restrict__ src,
                        const int* __restrict__ dst, const float* __restrict__ araw,
                        const float* __restrict__ amax, float* __restrict__ accum,
                        float* __restrict__ asum) {
  int idx = blockIdx.x * 16 + (threadIdx.x >> 4);
  int dq = threadIdx.x & 15;
  if (idx >= NE + NN) return;
  int s, t;
  if (idx < NE) { s = src[idx]; t = dst[idx]; }
  else          { s = t = idx - NE; }
  int h = dq >> 2;
  float w = expf(araw[(size_t)idx * NH + h] - amax[t * NH + h]);
  float4 x = *(const float4*)(xh + (size_t)s * DD + dq * 4);
  float* ap = accum + (size_t)t * DD + dq * 4;
  atomicAdd(ap + 0, w * x.x);
  atomicAdd(ap + 1, w * x.y);
  atomicAdd(ap + 2, w * x.z);
  atomicAdd(ap + 3, w * x.w);
  if ((dq & 3) == 0) atomicAdd(&asum[t * NH + h], w);
}

__global__ void k_node_fin(float* __restrict__ nf, const float* __restrict__ accum,
                           const float* __restrict__ asum, const float* __restrict__ cb,
                           const float* __restrict__ g, const float* __restrict__ b) {
  int t = blockIdx.x * 4 + (threadIdx.x >> 6);
  int d = threadIdx.x & 63;
  if (t >= NN) return;
  int h = d >> 4;
  float val = accum[t * DD + d] / (asum[t * NH + h] + 1e-16f) + cb[d];
  float m = val;
#pragma unroll
  for (int off = 32; off >= 1; off >>= 1) m += __shfl_xor(m, off, 64);
  m *= (1.f / 64.f);
  float c = val - m;
  float q = c * c;
#pragma unroll
  for (int off = 32; off >= 1; off >>= 1) q += __shfl_xor(q, off, 64);
  float rstd = 1.f / sqrtf(q * (1.f / 64.f) + 1e-5f);
  float y = c * rstd * g[d] + b[d];
  y = fmaxf(y, 0.f);
  nf[t * DD + d] = y + nf[t * DD + d];
}

// ---------------- edge MLP: N-split across waves (disjoint W slices) ----------
// block = 64 edges, 4 waves. Wave w owns GEMM1 cols w*48..w*48+47 (t = w*3..w*3+2)
// and GEMM2 cols w*16..w*16+15 (t = w), for ALL 64 rows.
// X staged in LDS as bf16 hi/lo planes; H single-bf16 plane; residual = hi+lo.
__global__ __launch_bounds__(256, 2) void k_edge_mlp2(
    const float* __restrict__ nf, float* __restrict__ ef,
    const int* __restrict__ src, const int* __restrict__ dst,
    const __bf16* __restrict__ W1P, const float* __restrict__ b1,
    const float* __restrict__ g, const float* __restrict__ bg,
    const __bf16* __restrict__ W2P, const float* __restrict__ b2) {
  __shared__ __bf16 Xhi[64 * 200];   // 25.6 KB each; stride 200 bf16 = 400 B (2-way alias only)
  __shared__ __bf16 Xlo[64 * 200];
  __shared__ __bf16 Hs[64 * 200];
  __shared__ float P[64 * 8];        // per-row LN partials: [row][wave*2 + {sm,sq}]
  int tid = threadIdx.x;
  int e0 = blockIdx.x * 64;

  // stage X = [nf[src] | nf[dst] | ef] as hi/lo bf16 planes
  for (int idx = tid; idx < 64 * 48; idx += 256) {
    int row = idx / 48, q = idx % 48;
    const float4* sp;
    if (q < 16)      sp = (const float4*)(nf + (size_t)src[e0 + row] * DD) + q;
    else if (q < 32) sp = (const float4*)(nf + (size_t)dst[e0 + row] * DD) + (q - 16);
    else             sp = (const float4*)(ef + (size_t)(e0 + row) * DD) + (q - 32);
    float4 v = *sp;
    bf4 hi, lo;
    hi[0] = (__bf16)v.x; lo[0] = (__bf16)(v.x - (float)hi[0]);
    hi[1] = (__bf16)v.y; lo[1] = (__bf16)(v.y - (float)hi[1]);
    hi[2] = (__bf16)v.z; lo[2] = (__bf16)(v.z - (float)hi[2]);
    hi[3] = (__bf16)v.w; lo[3] = (__bf16)(v.w - (float)hi[3]);
    *(bf4*)&Xhi[row * 200 + q * 4] = hi;
    *(bf4*)&Xlo[row * 200 + q * 4] = lo;
  }
  __syncthreads();

  int w = tid >> 6, l = tid & 63;
  int gq = l >> 4, i = l & 15;

  // GEMM1: acc[rt][t], rows rt*16 + (C-layout), cols w*48 + t*16 + i
  f32x4 acc[4][3];
#pragma unroll
  for (int rt = 0; rt < 4; ++rt)
#pragma unroll
    for (int t = 0; t < 3; ++t) acc[rt][t] = (f32x4){0.f, 0.f, 0.f, 0.f};

  const bf8* w1v = (const bf8*)W1P;
#pragma unroll
  for (int s = 0; s < 6; ++s) {
    bf8 ah[4], al[4];
#pragma unroll
    for (int rt = 0; rt < 4; ++rt) {
      int off = (rt * 16 + i) * 200 + s * 32 + gq * 8;
      ah[rt] = *(const bf8*)&Xhi[off];
      al[rt] = *(const bf8*)&Xlo[off];
    }
#pragma unroll
    for (int t = 0; t < 3; ++t) {
      int base = (((w * 3 + t) * 6 + s) * 64 + l) * 2;
      bf8 bh = w1v[base];
      bf8 bl = w1v[base + 1];
#pragma unroll
      for (int rt = 0; rt < 4; ++rt) {
        acc[rt][t] = MFMA(ah[rt], bh, acc[rt][t]);
        acc[rt][t] = MFMA(al[rt], bh, acc[rt][t]);
        acc[rt][t] = MFMA(ah[rt], bl, acc[rt][t]);
      }
    }
  }

  // + b1; per-row LN partials (this wave covers 48 of 192 cols)
  float b1v[3], gv[3], bgv[3];
#pragma unroll
  for (int t = 0; t < 3; ++t) {
    int n = w * 48 + t * 16 + i;
    b1v[t] = b1[n]; gv[t] = g[n]; bgv[t] = bg[n];
  }
#pragma unroll
  for (int rt = 0; rt < 4; ++rt)
#pragma unroll
    for (int t = 0; t < 3; ++t)
#pragma unroll
      for (int r = 0; r < 4; ++r) acc[rt][t][r] += b1v[t];

#pragma unroll
  for (int rt = 0; rt < 4; ++rt)
#pragma unroll
    for (int r = 0; r < 4; ++r) {
      float sm = 0.f, sq = 0.f;
#pragma unroll
      for (int t = 0; t < 3; ++t) { float x = acc[rt][t][r]; sm += x; sq = fmaf(x, x, sq); }
#pragma unroll
      for (int off = 1; off <= 8; off <<= 1) {
        sm += __shfl_xor(sm, off, 64);
        sq += __shfl_xor(sq, off, 64);
      }
      if (i == 0) {
        int row = rt * 16 + gq * 4 + r;
        P[row * 8 + w * 2]     = sm;
        P[row * 8 + w * 2 + 1] = sq;
      }
    }
  __syncthreads();

  // finalize LN, relu, write H (bf16)
#pragma unroll
  for (int rt = 0; rt < 4; ++rt)
#pragma unroll
    for (int r = 0; r < 4; ++r) {
      int row = rt * 16 + gq * 4 + r;
      float4 p0 = *(const float4*)&P[row * 8];
      float4 p1 = *(const float4*)&P[row * 8 + 4];
      float sm = p0.x + p0.z + p1.x + p1.z;
      float sq = p0.y + p0.w + p1.y + p1.w;
      float mean = sm * (1.f / (float)DIN);
      float var = sq * (1.f / (float)DIN) - mean * mean;
      float rstd = 1.f / sqrtf(var + 1e-5f);
#pragma unroll
      for (int t = 0; t < 3; ++t) {
        float y = (acc[rt][t][r] - mean) * rstd * gv[t] + bgv[t];
        y = fmaxf(y, 0.f);
        Hs[row * 200 + w * 48 + t * 16 + i] = (__bf16)y;
      }
    }
  __syncthreads();

  // GEMM2: cols w*16 + i, all 64 rows
  f32x4 acc2[4];
#pragma unroll
  for (int rt = 0; rt < 4; ++rt) acc2[rt] = (f32x4){0.f, 0.f, 0.f, 0.f};

  const bf8* w2v = (const bf8*)W2P;
#pragma unroll
  for (int s = 0; s < 6; ++s) {
    bf8 a2[4];
#pragma unroll
    for (int rt = 0; rt < 4; ++rt)
      a2[rt] = *(const bf8*)&Hs[(rt * 16 + i) * 200 + s * 32 + gq * 8];
    int base = ((w * 6 + s) * 64 + l) * 2;
    bf8 bh = w2v[base];
    bf8 bl = w2v[base + 1];
#pragma unroll
    for (int rt = 0; rt < 4; ++rt) {
      acc2[rt] = MFMA(a2[rt], bh, acc2[rt]);
      acc2[rt] = MFMA(a2[rt], bl, acc2[rt]);
    }
  }

  float b2v = b2[w * 16 + i];
  int col = w * 16 + i;
#pragma unroll
  for (int rt = 0; rt < 4; ++rt)
#pragma unroll
    for (int r = 0; r < 4; ++r) {
      int row = rt * 16 + gq * 4 + r;
      int xoff = row * 200 + 128 + col;
      float res = acc2[rt][r] + b2v + (float)Xhi[xoff] + (float)Xlo[xoff];
      ef[(size_t)(e0 + row) * DD + col] = res;
    }
}

extern "C" void kernel_launch(void* const* d_in, const int* in_sizes, int n_in,
                              void* d_out, int out_size, void* d_ws, size_t ws_size,
                              hipStream_t stream) {
  const float* node_feats = (const float*)d_in[0];
  const float* edge_feats = (const float*)d_in[1];
  const int*   edge_index = (const int*)d_in[2];
  const float* conv_w  = (const float*)d_in[3];
  const float* att_src = (const float*)d_in[4];
  const float* att_dst = (const float*)d_in[5];
  const float* edge_w  = (const float*)d_in[6];
  const float* att_edge= (const float*)d_in[7];
  const float* conv_b  = (const float*)d_in[8];
  const float* ln_g    = (const float*)d_in[9];
  const float* ln_b    = (const float*)d_in[10];
  const float* up1_w   = (const float*)d_in[11];
  const float* up1_b   = (const float*)d_in[12];
  const float* up_ln_g = (const float*)d_in[13];
  const float* up_ln_b = (const float*)d_in[14];
  const float* up2_w   = (const float*)d_in[15];
  const float* up2_b   = (const float*)d_in[16];

  const int* src = edge_index;
  const int* dst = edge_index + NE;

  float* nf = (float*)d_out;
  float* ef = nf + (size_t)NN * DD;

  float* w = (float*)d_ws;
  float* xh    = w; w += (size_t)NN * DD;
  float* asrc  = w; w += (size_t)NN * NH;
  float* adst  = w; w += (size_t)NN * NH;
  float* araw  = w; w += (size_t)(NE + NN) * NH;
  float* amax  = w; w += (size_t)NN * NH;
  float* asum  = w; w += (size_t)NN * NH;
  float* accum = w; w += (size_t)NN * DD;
  float* vbuf  = w; w += 256;
  __bf16* W1P = (__bf16*)w; w += (size_t)4 * 73728 / 2;
  __bf16* W2P = (__bf16*)w; w += (size_t)4 * 24576 / 2;

  hipMemcpyAsync(nf, node_feats, (size_t)NN * DD * sizeof(float),
                 hipMemcpyDeviceToDevice, stream);
  hipMemcpyAsync(ef, edge_feats, (size_t)NE * DD * sizeof(float),
                 hipMemcpyDeviceToDevice, stream);

  k_pack_w1<<<72, 256, 0, stream>>>(up1_w, W1P);
  k_pack_w2<<<24, 256, 0, stream>>>(up2_w, W2P);

  for (int l = 0; l < NL; ++l) {
    k_compute_v<<<1, 256, 0, stream>>>(edge_w + (size_t)l * DD * DD,
                                       att_edge + (size_t)l * NH * NC, vbuf);
    k_xh<<<NN / 4, 256, 0, stream>>>(nf, conv_w + (size_t)l * DD * DD,
                                     att_src + (size_t)l * NH * NC,
                                     att_dst + (size_t)l * NH * NC, xh, asrc, adst);
    k_fill<<<(NN * DD + 255) / 256, 256, 0, stream>>>(accum, amax, asum);
    k_pass1<<<(NE + NN + 63) / 64, 256, 0, stream>>>(ef, src, dst, vbuf, asrc, adst, araw, amax);
    k_pass2<<<(NE + NN + 15) / 16, 256, 0, stream>>>(xh, src, dst, araw, amax, accum, asum);
    k_node_fin<<<NN / 4, 256, 0, stream>>>(nf, accum, asum, conv_b + (size_t)l * DD,
                                           ln_g + (size_t)l * DD, ln_b + (size_t)l * DD);
    k_edge_mlp2<<<NE / 64, 256, 0, stream>>>(
        nf, ef, src, dst,
        W1P + (size_t)l * 73728, up1_b + (size_t)l * DIN,
        up_ln_g + (size_t)l * DIN, up_ln_b + (size_t)l * DIN,
        W2P + (size_t)l * 24576, up2_b + (size_t)l * DD);
  }
}

// Round 5
// 6403.121 us; speedup vs baseline: 2.0822x; 2.0822x over previous
//
#include <hip/hip_runtime.h>
#include <math.h>

#define NN 100000
#define NE 1600000
#define DD 64
#define NL 4
#define NH 4
#define NC 16
#define DIN 192
#define SLOPE 0.2f

typedef __bf16 bf8 __attribute__((ext_vector_type(8)));
typedef __bf16 bf4 __attribute__((ext_vector_type(4)));
typedef float f32x4 __attribute__((ext_vector_type(4)));

__device__ __forceinline__ f32x4 MFMA(bf8 a, bf8 b, f32x4 c) {
  return __builtin_amdgcn_mfma_f32_16x16x32_bf16(a, b, c, 0, 0, 0);
}

// ---------------- weight packing into MFMA B-fragment layout ----------------
__global__ void k_pack_w1(const float* __restrict__ W1, __bf16* __restrict__ W1P) {
  int gidx = blockIdx.x * 256 + threadIdx.x;
  if (gidx >= 4 * 4608) return;
  int lyr = gidx / 4608, rem = gidx % 4608;
  int lane = rem & 63, ts = rem >> 6;
  int s = ts % 6, t = ts / 6;
  const float* Wl = W1 + (size_t)lyr * DIN * DIN;
  __bf16* out = W1P + (size_t)lyr * 73728 + ((size_t)(t * 6 + s) * 64 + lane) * 16;
  int k0 = s * 32 + (lane >> 4) * 8, n = t * 16 + (lane & 15);
#pragma unroll
  for (int j = 0; j < 8; ++j) {
    float v = Wl[(size_t)(k0 + j) * DIN + n];
    __bf16 h = (__bf16)v;
    out[j] = h;
    out[8 + j] = (__bf16)(v - (float)h);
  }
}

__global__ void k_pack_w2(const float* __restrict__ W2, __bf16* __restrict__ W2P) {
  int gidx = blockIdx.x * 256 + threadIdx.x;
  if (gidx >= 4 * 1536) return;
  int lyr = gidx / 1536, rem = gidx % 1536;
  int lane = rem & 63, ts = rem >> 6;
  int s = ts % 6, t = ts / 6;
  const float* Wl = W2 + (size_t)lyr * DIN * DD;
  __bf16* out = W2P + (size_t)lyr * 24576 + ((size_t)(t * 6 + s) * 64 + lane) * 16;
  int k0 = s * 32 + (lane >> 4) * 8, n = t * 16 + (lane & 15);
#pragma unroll
  for (int j = 0; j < 8; ++j) {
    float v = Wl[(size_t)(k0 + j) * DD + n];
    __bf16 h = (__bf16)v;
    out[j] = h;
    out[8 + j] = (__bf16)(v - (float)h);
  }
}

// ---------------- CSR build (once per launch; graph is static) ----------------
__global__ void k_zero(int* __restrict__ deg) {
  int i = blockIdx.x * 256 + threadIdx.x;
  if (i < NN) deg[i] = 0;
}

__global__ void k_hist(const int* __restrict__ dst, int* __restrict__ deg) {
  int e = blockIdx.x * 256 + threadIdx.x;
  if (e < NE) atomicAdd(&deg[dst[e]], 1);
}

// block-local exclusive scan over 1024 elements (256 thr x 4)
__global__ void k_scan1(const int* __restrict__ deg, int* __restrict__ offs,
                        int* __restrict__ bsum) {
  __shared__ int sh[256];
  int t = threadIdx.x, b = blockIdx.x;
  int i0 = b * 1024 + t * 4;
  int d0 = (i0 + 0 < NN) ? deg[i0 + 0] : 0;
  int d1 = (i0 + 1 < NN) ? deg[i0 + 1] : 0;
  int d2 = (i0 + 2 < NN) ? deg[i0 + 2] : 0;
  int d3 = (i0 + 3 < NN) ? deg[i0 + 3] : 0;
  int s4 = d0 + d1 + d2 + d3;
  sh[t] = s4;
  __syncthreads();
  // exclusive scan of sh[256]
  int p = 0;
#pragma unroll
  for (int off = 1; off < 256; off <<= 1) {
    int v = (t >= off) ? sh[t - off] : 0;
    __syncthreads();
    sh[t] += v;
    __syncthreads();
  }
  p = sh[t] - s4;  // exclusive
  if (t == 255) bsum[b] = sh[255];
  if (i0 + 0 < NN) offs[i0 + 0] = p;
  if (i0 + 1 < NN) offs[i0 + 1] = p + d0;
  if (i0 + 2 < NN) offs[i0 + 2] = p + d0 + d1;
  if (i0 + 3 < NN) offs[i0 + 3] = p + d0 + d1 + d2;
}

__global__ void k_scan2(int* __restrict__ bsum, int* __restrict__ boff,
                        int* __restrict__ offs, int nb) {
  if (threadIdx.x == 0 && blockIdx.x == 0) {
    int run = 0;
    for (int k = 0; k < nb; ++k) { boff[k] = run; run += bsum[k]; }
    offs[NN] = NE;
  }
}

__global__ void k_scan3(int* __restrict__ offs, const int* __restrict__ boff,
                        int* __restrict__ cursor) {
  int i = blockIdx.x * 256 + threadIdx.x;
  if (i < NN) {
    int v = offs[i] + boff[i >> 10];
    offs[i] = v;
    cursor[i] = v;
  }
}

__global__ void k_scatter(const int* __restrict__ src, const int* __restrict__ dst,
                          int* __restrict__ cursor, int* __restrict__ csr_src,
                          int* __restrict__ posmap) {
  int e = blockIdx.x * 256 + threadIdx.x;
  if (e >= NE) return;
  int pos = atomicAdd(&cursor[dst[e]], 1);
  csr_src[pos] = src[e];
  posmap[e] = pos;
}

// ---------------- GAT conv path ----------------
__global__ void k_compute_v(const float* __restrict__ ew, const float* __restrict__ ae,
                            float* __restrict__ v) {
  int d = threadIdx.x >> 2, h = threadIdx.x & 3;
  float s = 0.f;
#pragma unroll
  for (int c = 0; c < NC; ++c) s = fmaf(ew[d * DD + h * NC + c], ae[h * NC + c], s);
  v[d * NH + h] = s;
}

__global__ void k_xh(const float* __restrict__ nf, const float* __restrict__ W,
                     const float* __restrict__ as_, const float* __restrict__ ad_,
                     float* __restrict__ xh, float* __restrict__ asrc,
                     float* __restrict__ adst) {
  int t = blockIdx.x * 4 + (threadIdx.x >> 6);
  int d = threadIdx.x & 63;
  if (t >= NN) return;
  const float* x = nf + (size_t)t * DD;
  float acc = 0.f;
#pragma unroll
  for (int k = 0; k < DD; ++k) acc = fmaf(x[k], W[k * DD + d], acc);
  xh[(size_t)t * DD + d] = acc;
  int h = d >> 4, c = d & 15;
  float ps = acc * as_[h * NC + c];
  float pd = acc * ad_[h * NC + c];
#pragma unroll
  for (int off = 8; off >= 1; off >>= 1) {
    ps += __shfl_xor(ps, off, 64);
    pd += __shfl_xor(pd, off, 64);
  }
  if (c == 0) { asrc[t * NH + h] = ps; adst[t * NH + h] = pd; }
}

// pass1: alpha_raw per (edge, head) written into CSR position (posmap)
__global__ void k_pass1(const float* __restrict__ ef, const int* __restrict__ src,
                        const int* __restrict__ dst, const float* __restrict__ v,
                        const float* __restrict__ asrc, const float* __restrict__ adst,
                        const int* __restrict__ posmap, float* __restrict__ araw) {
  int e = blockIdx.x * 64 + (threadIdx.x >> 2);
  int part = threadIdx.x & 3;
  if (e >= NE) return;
  int s = src[e], t = dst[e];
  float ph0 = 0.f, ph1 = 0.f, ph2 = 0.f, ph3 = 0.f;
  const float4* ep = (const float4*)(ef + (size_t)e * DD + part * 16);
  const float4* v4 = (const float4*)v;
#pragma unroll
  for (int c4 = 0; c4 < 4; ++c4) {
    float4 x = ep[c4];
    int d0 = part * 16 + c4 * 4;
    float4 va = v4[d0], vb = v4[d0 + 1], vc = v4[d0 + 2], vd = v4[d0 + 3];
    ph0 = fmaf(x.x, va.x, fmaf(x.y, vb.x, fmaf(x.z, vc.x, fmaf(x.w, vd.x, ph0))));
    ph1 = fmaf(x.x, va.y, fmaf(x.y, vb.y, fmaf(x.z, vc.y, fmaf(x.w, vd.y, ph1))));
    ph2 = fmaf(x.x, va.z, fmaf(x.y, vb.z, fmaf(x.z, vc.z, fmaf(x.w, vd.z, ph2))));
    ph3 = fmaf(x.x, va.w, fmaf(x.y, vb.w, fmaf(x.z, vc.w, fmaf(x.w, vd.w, ph3))));
  }
#pragma unroll
  for (int off = 1; off <= 2; off <<= 1) {
    ph0 += __shfl_xor(ph0, off, 64);
    ph1 += __shfl_xor(ph1, off, 64);
    ph2 += __shfl_xor(ph2, off, 64);
    ph3 += __shfl_xor(ph3, off, 64);
  }
  float pe = (part == 0) ? ph0 : (part == 1) ? ph1 : (part == 2) ? ph2 : ph3;
  float a = asrc[s * NH + part] + adst[t * NH + part] + pe;
  a = (a > 0.f) ? a : SLOPE * a;
  araw[(size_t)posmap[e] * NH + part] = a;
}

// fused: segment softmax + weighted gather + conv_b + LN + relu + residual.
// 1 wave per node (lane = d). CSR-contiguous araw; zero atomics.
__global__ __launch_bounds__(256) void k_gather(
    const float* __restrict__ xh, const float* __restrict__ araw,
    const int* __restrict__ csr_src, const int* __restrict__ offs,
    const float* __restrict__ asrc, const float* __restrict__ adst,
    const float* __restrict__ cb, const float* __restrict__ g,
    const float* __restrict__ bln, float* __restrict__ nf) {
  int t = blockIdx.x * 4 + (threadIdx.x >> 6);
  int d = threadIdx.x & 63;
  if (t >= NN) return;
  int h = d >> 4;
  int o0 = offs[t], o1 = offs[t + 1];
  int deg = o1 - o0;

  // phase A: per-head max over neighbors (lane-parallel, stride 64)
  float m0 = -INFINITY, m1 = -INFINITY, m2 = -INFINITY, m3 = -INFINITY;
  for (int base = 0; base < deg; base += 64) {
    int j = base + d;
    if (j < deg) {
      float4 a = *(const float4*)(araw + (size_t)(o0 + j) * NH);
      m0 = fmaxf(m0, a.x); m1 = fmaxf(m1, a.y);
      m2 = fmaxf(m2, a.z); m3 = fmaxf(m3, a.w);
    }
  }
#pragma unroll
  for (int off = 32; off >= 1; off >>= 1) {
    m0 = fmaxf(m0, __shfl_xor(m0, off, 64));
    m1 = fmaxf(m1, __shfl_xor(m1, off, 64));
    m2 = fmaxf(m2, __shfl_xor(m2, off, 64));
    m3 = fmaxf(m3, __shfl_xor(m3, off, 64));
  }
  // self-loop alpha (edge attr = 0): leaky(asrc[t]+adst[t])
  float sh = asrc[t * NH + h] + adst[t * NH + h];
  sh = (sh > 0.f) ? sh : SLOPE * sh;
  float mh = (h == 0) ? m0 : (h == 1) ? m1 : (h == 2) ? m2 : m3;
  mh = fmaxf(mh, sh);

  // phase B: serial over neighbors; coalesced xh row per edge
  float acc = 0.f, wsum = 0.f;
  int j = 0;
  for (; j + 1 < deg; j += 2) {
    int sp0 = csr_src[o0 + j], sp1 = csr_src[o0 + j + 1];
    float ar0 = araw[(size_t)(o0 + j) * NH + h];
    float ar1 = araw[(size_t)(o0 + j + 1) * NH + h];
    float w0 = expf(ar0 - mh), w1 = expf(ar1 - mh);
    acc = fmaf(w0, xh[(size_t)sp0 * DD + d], acc);
    acc = fmaf(w1, xh[(size_t)sp1 * DD + d], acc);
    wsum += w0 + w1;
  }
  if (j < deg) {
    int sp = csr_src[o0 + j];
    float ar = araw[(size_t)(o0 + j) * NH + h];
    float w = expf(ar - mh);
    acc = fmaf(w, xh[(size_t)sp * DD + d], acc);
    wsum += w;
  }
  float wself = expf(sh - mh);
  acc = fmaf(wself, xh[(size_t)t * DD + d], acc);
  wsum += wself;

  float val = acc / (wsum + 1e-16f) + cb[d];
  // LayerNorm over 64 dims
  float m = val;
#pragma unroll
  for (int off = 32; off >= 1; off >>= 1) m += __shfl_xor(m, off, 64);
  m *= (1.f / 64.f);
  float c = val - m;
  float q = c * c;
#pragma unroll
  for (int off = 32; off >= 1; off >>= 1) q += __shfl_xor(q, off, 64);
  float rstd = 1.f / sqrtf(q * (1.f / 64.f) + 1e-5f);
  float y = c * rstd * g[d] + bln[d];
  y = fmaxf(y, 0.f);
  nf[(size_t)t * DD + d] = y + nf[(size_t)t * DD + d];
}

// ---------------- edge MLP: N-split waves, Hs aliased onto Xlo (3 blocks/CU) ----
__global__ __launch_bounds__(256, 3) void k_edge_mlp2(
    const float* __restrict__ nf, float* __restrict__ ef,
    const int* __restrict__ src, const int* __restrict__ dst,
    const __bf16* __restrict__ W1P, const float* __restrict__ b1,
    const float* __restrict__ g, const float* __restrict__ bg,
    const __bf16* __restrict__ W2P, const float* __restrict__ b2) {
  __shared__ __bf16 Xhi[64 * 200];     // 25.6 KB
  __shared__ __bf16 XloHs[64 * 200];   // Xlo during GEMM1; reused as Hs after
  __shared__ float P[64 * 8];          // 2 KB LN partials -> total 52 KB, 3 blocks/CU
  int tid = threadIdx.x;
  int e0 = blockIdx.x * 64;

  for (int idx = tid; idx < 64 * 48; idx += 256) {
    int row = idx / 48, q = idx % 48;
    const float4* sp;
    if (q < 16)      sp = (const float4*)(nf + (size_t)src[e0 + row] * DD) + q;
    else if (q < 32) sp = (const float4*)(nf + (size_t)dst[e0 + row] * DD) + (q - 16);
    else             sp = (const float4*)(ef + (size_t)(e0 + row) * DD) + (q - 32);
    float4 v = *sp;
    bf4 hi, lo;
    hi[0] = (__bf16)v.x; lo[0] = (__bf16)(v.x - (float)hi[0]);
    hi[1] = (__bf16)v.y; lo[1] = (__bf16)(v.y - (float)hi[1]);
    hi[2] = (__bf16)v.z; lo[2] = (__bf16)(v.z - (float)hi[2]);
    hi[3] = (__bf16)v.w; lo[3] = (__bf16)(v.w - (float)hi[3]);
    *(bf4*)&Xhi[row * 200 + q * 4] = hi;
    *(bf4*)&XloHs[row * 200 + q * 4] = lo;
  }
  __syncthreads();

  int w = tid >> 6, l = tid & 63;
  int gq = l >> 4, i = l & 15;

  f32x4 acc[4][3];
#pragma unroll
  for (int rt = 0; rt < 4; ++rt)
#pragma unroll
    for (int t = 0; t < 3; ++t) acc[rt][t] = (f32x4){0.f, 0.f, 0.f, 0.f};

  const bf8* w1v = (const bf8*)W1P;
#pragma unroll
  for (int s = 0; s < 6; ++s) {
    bf8 ah[4], al[4];
#pragma unroll
    for (int rt = 0; rt < 4; ++rt) {
      int off = (rt * 16 + i) * 200 + s * 32 + gq * 8;
      ah[rt] = *(const bf8*)&Xhi[off];
      al[rt] = *(const bf8*)&XloHs[off];
    }
#pragma unroll
    for (int t = 0; t < 3; ++t) {
      int base = (((w * 3 + t) * 6 + s) * 64 + l) * 2;
      bf8 bh = w1v[base];
      bf8 bl = w1v[base + 1];
#pragma unroll
      for (int rt = 0; rt < 4; ++rt) {
        acc[rt][t] = MFMA(ah[rt], bh, acc[rt][t]);
        acc[rt][t] = MFMA(al[rt], bh, acc[rt][t]);
        acc[rt][t] = MFMA(ah[rt], bl, acc[rt][t]);
      }
    }
  }

  float b1v[3], gv[3], bgv[3];
#pragma unroll
  for (int t = 0; t < 3; ++t) {
    int n = w * 48 + t * 16 + i;
    b1v[t] = b1[n]; gv[t] = g[n]; bgv[t] = bg[n];
  }
#pragma unroll
  for (int rt = 0; rt < 4; ++rt)
#pragma unroll
    for (int t = 0; t < 3; ++t)
#pragma unroll
      for (int r = 0; r < 4; ++r) acc[rt][t][r] += b1v[t];

#pragma unroll
  for (int rt = 0; rt < 4; ++rt)
#pragma unroll
    for (int r = 0; r < 4; ++r) {
      float sm = 0.f, sq = 0.f;
#pragma unroll
      for (int t = 0; t < 3; ++t) { float x = acc[rt][t][r]; sm += x; sq = fmaf(x, x, sq); }
#pragma unroll
      for (int off = 1; off <= 8; off <<= 1) {
        sm += __shfl_xor(sm, off, 64);
        sq += __shfl_xor(sq, off, 64);
      }
      if (i == 0) {
        int row = rt * 16 + gq * 4 + r;
        P[row * 8 + w * 2]     = sm;
        P[row * 8 + w * 2 + 1] = sq;
      }
    }
  __syncthreads();

  // LN finalize (y stored back into acc); stash ef residual before Hs overwrite
  int col = w * 16 + i;
  float res[4][4];
#pragma unroll
  for (int rt = 0; rt < 4; ++rt)
#pragma unroll
    for (int r = 0; r < 4; ++r) {
      int row = rt * 16 + gq * 4 + r;
      float4 p0 = *(const float4*)&P[row * 8];
      float4 p1 = *(const float4*)&P[row * 8 + 4];
      float sm = p0.x + p0.z + p1.x + p1.z;
      float sq = p0.y + p0.w + p1.y + p1.w;
      float mean = sm * (1.f / (float)DIN);
      float var = sq * (1.f / (float)DIN) - mean * mean;
      float rstd = 1.f / sqrtf(var + 1e-5f);
#pragma unroll
      for (int t = 0; t < 3; ++t) {
        float y = (acc[rt][t][r] - mean) * rstd * gv[t] + bgv[t];
        acc[rt][t][r] = fmaxf(y, 0.f);
      }
      int xoff = row * 200 + 128 + col;
      res[rt][r] = (float)Xhi[xoff] + (float)XloHs[xoff];
    }
  __syncthreads();  // all Xlo reads done

#pragma unroll
  for (int rt = 0; rt < 4; ++rt)
#pragma unroll
    for (int r = 0; r < 4; ++r) {
      int row = rt * 16 + gq * 4 + r;
#pragma unroll
      for (int t = 0; t < 3; ++t)
        XloHs[row * 200 + w * 48 + t * 16 + i] = (__bf16)acc[rt][t][r];
    }
  __syncthreads();  // Hs ready

  f32x4 acc2[4];
#pragma unroll
  for (int rt = 0; rt < 4; ++rt) acc2[rt] = (f32x4){0.f, 0.f, 0.f, 0.f};

  const bf8* w2v = (const bf8*)W2P;
#pragma unroll
  for (int s = 0; s < 6; ++s) {
    bf8 a2[4];
#pragma unroll
    for (int rt = 0; rt < 4; ++rt)
      a2[rt] = *(const bf8*)&XloHs[(rt * 16 + i) * 200 + s * 32 + gq * 8];
    int base = ((w * 6 + s) * 64 + l) * 2;
    bf8 bh = w2v[base];
    bf8 bl = w2v[base + 1];
#pragma unroll
    for (int rt = 0; rt < 4; ++rt) {
      acc2[rt] = MFMA(a2[rt], bh, acc2[rt]);
      acc2[rt] = MFMA(a2[rt], bl, acc2[rt]);
    }
  }

  float b2v = b2[col];
#pragma unroll
  for (int rt = 0; rt < 4; ++rt)
#pragma unroll
    for (int r = 0; r < 4; ++r) {
      int row = rt * 16 + gq * 4 + r;
      float out = acc2[rt][r] + b2v + res[rt][r];
      ef[(size_t)(e0 + row) * DD + col] = out;
    }
}

extern "C" void kernel_launch(void* const* d_in, const int* in_sizes, int n_in,
                              void* d_out, int out_size, void* d_ws, size_t ws_size,
                              hipStream_t stream) {
  const float* node_feats = (const float*)d_in[0];
  const float* edge_feats = (const float*)d_in[1];
  const int*   edge_index = (const int*)d_in[2];
  const float* conv_w  = (const float*)d_in[3];
  const float* att_src = (const float*)d_in[4];
  const float* att_dst = (const float*)d_in[5];
  const float* edge_w  = (const float*)d_in[6];
  const float* att_edge= (const float*)d_in[7];
  const float* conv_b  = (const float*)d_in[8];
  const float* ln_g    = (const float*)d_in[9];
  const float* ln_b    = (const float*)d_in[10];
  const float* up1_w   = (const float*)d_in[11];
  const float* up1_b   = (const float*)d_in[12];
  const float* up_ln_g = (const float*)d_in[13];
  const float* up_ln_b = (const float*)d_in[14];
  const float* up2_w   = (const float*)d_in[15];
  const float* up2_b   = (const float*)d_in[16];

  const int* src = edge_index;
  const int* dst = edge_index + NE;

  float* nf = (float*)d_out;
  float* ef = nf + (size_t)NN * DD;

  float* w = (float*)d_ws;
  float* xh    = w; w += (size_t)NN * DD;
  float* asrc  = w; w += (size_t)NN * NH;
  float* adst  = w; w += (size_t)NN * NH;
  float* araw  = w; w += (size_t)NE * NH;
  float* vbuf  = w; w += 256;
  __bf16* W1P = (__bf16*)w; w += (size_t)4 * 73728 / 2;
  __bf16* W2P = (__bf16*)w; w += (size_t)4 * 24576 / 2;
  int* deg     = (int*)w; w += NN;
  int* offs    = (int*)w; w += NN + 1;
  int* cursor  = (int*)w; w += NN;
  int* bsum    = (int*)w; w += 128;
  int* boff    = (int*)w; w += 128;
  int* csr_src = (int*)w; w += NE;
  int* posmap  = (int*)w; w += NE;

  hipMemcpyAsync(nf, node_feats, (size_t)NN * DD * sizeof(float),
                 hipMemcpyDeviceToDevice, stream);
  hipMemcpyAsync(ef, edge_feats, (size_t)NE * DD * sizeof(float),
                 hipMemcpyDeviceToDevice, stream);

  k_pack_w1<<<72, 256, 0, stream>>>(up1_w, W1P);
  k_pack_w2<<<24, 256, 0, stream>>>(up2_w, W2P);

  // CSR build (static graph; once per launch)
  const int nb = (NN + 1023) / 1024;  // 98
  k_zero<<<(NN + 255) / 256, 256, 0, stream>>>(deg);
  k_hist<<<(NE + 255) / 256, 256, 0, stream>>>(dst, deg);
  k_scan1<<<nb, 256, 0, stream>>>(deg, offs, bsum);
  k_scan2<<<1, 64, 0, stream>>>(bsum, boff, offs, nb);
  k_scan3<<<(NN + 255) / 256, 256, 0, stream>>>(offs, boff, cursor);
  k_scatter<<<(NE + 255) / 256, 256, 0, stream>>>(src, dst, cursor, csr_src, posmap);

  for (int l = 0; l < NL; ++l) {
    k_compute_v<<<1, 256, 0, stream>>>(edge_w + (size_t)l * DD * DD,
                                       att_edge + (size_t)l * NH * NC, vbuf);
    k_xh<<<NN / 4, 256, 0, stream>>>(nf, conv_w + (size_t)l * DD * DD,
                                     att_src + (size_t)l * NH * NC,
                                     att_dst + (size_t)l * NH * NC, xh, asrc, adst);
    k_pass1<<<NE / 64, 256, 0, stream>>>(ef, src, dst, vbuf, asrc, adst, posmap, araw);
    k_gather<<<NN / 4, 256, 0, stream>>>(xh, araw, csr_src, offs, asrc, adst,
                                         conv_b + (size_t)l * DD,
                                         ln_g + (size_t)l * DD,
                                         ln_b + (size_t)l * DD, nf);
    k_edge_mlp2<<<NE / 64, 256, 0, stream>>>(
        nf, ef, src, dst,
        W1P + (size_t)l * 73728, up1_b + (size_t)l * DIN,
        up_ln_g + (size_t)l * DIN, up_ln_b + (size_t)l * DIN,
        W2P + (size_t)l * 24576, up2_b + (size_t)l * DD);
  }
}

// Round 6
// 5992.138 us; speedup vs baseline: 2.2250x; 1.0686x over previous
//
#include <hip/hip_runtime.h>
#include <math.h>

#define NN 100000
#define NE 1600000
#define DD 64
#define NL 4
#define NH 4
#define NC 16
#define DIN 192
#define SLOPE 0.2f
#define EB 128
#define XSTR 200

typedef __bf16 bf8 __attribute__((ext_vector_type(8)));
typedef __bf16 bf4 __attribute__((ext_vector_type(4)));
typedef float f32x4 __attribute__((ext_vector_type(4)));

__device__ __forceinline__ f32x4 MFMA(bf8 a, bf8 b, f32x4 c) {
  return __builtin_amdgcn_mfma_f32_16x16x32_bf16(a, b, c, 0, 0, 0);
}

// ---------------- weight packing: separate hi/lo planes, 1KB tiles -----------
// tile (t,s): lane l holds W[k][n], k=s*32+(l>>4)*8+j, n=t*16+(l&15), j=0..7
// plane offset: ((t*6+s)*64 + l)*8 + j   (512 bf16 = 1KB per tile)
__global__ void k_pack_w1(const float* __restrict__ W1, __bf16* __restrict__ WH,
                          __bf16* __restrict__ WL) {
  int gidx = blockIdx.x * 256 + threadIdx.x;   // 4 layers * 12t*6s*64 = 18432
  if (gidx >= 4 * 4608) return;
  int lyr = gidx / 4608, rem = gidx % 4608;
  int lane = rem & 63, ts = rem >> 6;
  int s = ts % 6, t = ts / 6;
  const float* Wl = W1 + (size_t)lyr * DIN * DIN;
  size_t base = (size_t)lyr * 36864 + ((size_t)(t * 6 + s) * 64 + lane) * 8;
  int k0 = s * 32 + (lane >> 4) * 8, n = t * 16 + (lane & 15);
#pragma unroll
  for (int j = 0; j < 8; ++j) {
    float v = Wl[(size_t)(k0 + j) * DIN + n];
    __bf16 h = (__bf16)v;
    WH[base + j] = h;
    WL[base + j] = (__bf16)(v - (float)h);
  }
}

__global__ void k_pack_w2(const float* __restrict__ W2, __bf16* __restrict__ WH,
                          __bf16* __restrict__ WL) {
  int gidx = blockIdx.x * 256 + threadIdx.x;   // 4 layers * 4t*6s*64 = 6144
  if (gidx >= 4 * 1536) return;
  int lyr = gidx / 1536, rem = gidx % 1536;
  int lane = rem & 63, ts = rem >> 6;
  int s = ts % 6, t = ts / 6;
  const float* Wl = W2 + (size_t)lyr * DIN * DD;
  size_t base = (size_t)lyr * 12288 + ((size_t)(t * 6 + s) * 64 + lane) * 8;
  int k0 = s * 32 + (lane >> 4) * 8, n = t * 16 + (lane & 15);
#pragma unroll
  for (int j = 0; j < 8; ++j) {
    float v = Wl[(size_t)(k0 + j) * DD + n];
    __bf16 h = (__bf16)v;
    WH[base + j] = h;
    WL[base + j] = (__bf16)(v - (float)h);
  }
}

// ---------------- CSR build (once per launch; graph is static) ----------------
__global__ void k_zero(int* __restrict__ deg) {
  int i = blockIdx.x * 256 + threadIdx.x;
  if (i < NN) deg[i] = 0;
}

__global__ void k_hist(const int* __restrict__ dst, int* __restrict__ deg) {
  int e = blockIdx.x * 256 + threadIdx.x;
  if (e < NE) atomicAdd(&deg[dst[e]], 1);
}

__global__ void k_scan1(const int* __restrict__ deg, int* __restrict__ offs,
                        int* __restrict__ bsum) {
  __shared__ int sh[256];
  int t = threadIdx.x, b = blockIdx.x;
  int i0 = b * 1024 + t * 4;
  int d0 = (i0 + 0 < NN) ? deg[i0 + 0] : 0;
  int d1 = (i0 + 1 < NN) ? deg[i0 + 1] : 0;
  int d2 = (i0 + 2 < NN) ? deg[i0 + 2] : 0;
  int d3 = (i0 + 3 < NN) ? deg[i0 + 3] : 0;
  int s4 = d0 + d1 + d2 + d3;
  sh[t] = s4;
  __syncthreads();
  int p = 0;
#pragma unroll
  for (int off = 1; off < 256; off <<= 1) {
    int v = (t >= off) ? sh[t - off] : 0;
    __syncthreads();
    sh[t] += v;
    __syncthreads();
  }
  p = sh[t] - s4;
  if (t == 255) bsum[b] = sh[255];
  if (i0 + 0 < NN) offs[i0 + 0] = p;
  if (i0 + 1 < NN) offs[i0 + 1] = p + d0;
  if (i0 + 2 < NN) offs[i0 + 2] = p + d0 + d1;
  if (i0 + 3 < NN) offs[i0 + 3] = p + d0 + d1 + d2;
}

__global__ void k_scan2(int* __restrict__ bsum, int* __restrict__ boff,
                        int* __restrict__ offs, int nb) {
  if (threadIdx.x == 0 && blockIdx.x == 0) {
    int run = 0;
    for (int k = 0; k < nb; ++k) { boff[k] = run; run += bsum[k]; }
    offs[NN] = NE;
  }
}

__global__ void k_scan3(int* __restrict__ offs, const int* __restrict__ boff,
                        int* __restrict__ cursor) {
  int i = blockIdx.x * 256 + threadIdx.x;
  if (i < NN) {
    int v = offs[i] + boff[i >> 10];
    offs[i] = v;
    cursor[i] = v;
  }
}

__global__ void k_scatter(const int* __restrict__ src, const int* __restrict__ dst,
                          int* __restrict__ cursor, int* __restrict__ csr_src,
                          int* __restrict__ posmap) {
  int e = blockIdx.x * 256 + threadIdx.x;
  if (e >= NE) return;
  int pos = atomicAdd(&cursor[dst[e]], 1);
  csr_src[pos] = src[e];
  posmap[e] = pos;
}

// ---------------- GAT conv path ----------------
__global__ void k_compute_v(const float* __restrict__ ew, const float* __restrict__ ae,
                            float* __restrict__ v) {
  int d = threadIdx.x >> 2, h = threadIdx.x & 3;
  float s = 0.f;
#pragma unroll
  for (int c = 0; c < NC; ++c) s = fmaf(ew[d * DD + h * NC + c], ae[h * NC + c], s);
  v[d * NH + h] = s;
}

__global__ void k_xh(const float* __restrict__ nf, const float* __restrict__ W,
                     const float* __restrict__ as_, const float* __restrict__ ad_,
                     float* __restrict__ xh, float* __restrict__ asrc,
                     float* __restrict__ adst) {
  int t = blockIdx.x * 4 + (threadIdx.x >> 6);
  int d = threadIdx.x & 63;
  if (t >= NN) return;
  const float* x = nf + (size_t)t * DD;
  float acc = 0.f;
#pragma unroll
  for (int k = 0; k < DD; ++k) acc = fmaf(x[k], W[k * DD + d], acc);
  xh[(size_t)t * DD + d] = acc;
  int h = d >> 4, c = d & 15;
  float ps = acc * as_[h * NC + c];
  float pd = acc * ad_[h * NC + c];
#pragma unroll
  for (int off = 8; off >= 1; off >>= 1) {
    ps += __shfl_xor(ps, off, 64);
    pd += __shfl_xor(pd, off, 64);
  }
  if (c == 0) { asrc[t * NH + h] = ps; adst[t * NH + h] = pd; }
}

__global__ void k_pass1(const float* __restrict__ ef, const int* __restrict__ src,
                        const int* __restrict__ dst, const float* __restrict__ v,
                        const float* __restrict__ asrc, const float* __restrict__ adst,
                        const int* __restrict__ posmap, float* __restrict__ araw) {
  int e = blockIdx.x * 64 + (threadIdx.x >> 2);
  int part = threadIdx.x & 3;
  if (e >= NE) return;
  int s = src[e], t = dst[e];
  float ph0 = 0.f, ph1 = 0.f, ph2 = 0.f, ph3 = 0.f;
  const float4* ep = (const float4*)(ef + (size_t)e * DD + part * 16);
  const float4* v4 = (const float4*)v;
#pragma unroll
  for (int c4 = 0; c4 < 4; ++c4) {
    float4 x = ep[c4];
    int d0 = part * 16 + c4 * 4;
    float4 va = v4[d0], vb = v4[d0 + 1], vc = v4[d0 + 2], vd = v4[d0 + 3];
    ph0 = fmaf(x.x, va.x, fmaf(x.y, vb.x, fmaf(x.z, vc.x, fmaf(x.w, vd.x, ph0))));
    ph1 = fmaf(x.x, va.y, fmaf(x.y, vb.y, fmaf(x.z, vc.y, fmaf(x.w, vd.y, ph1))));
    ph2 = fmaf(x.x, va.z, fmaf(x.y, vb.z, fmaf(x.z, vc.z, fmaf(x.w, vd.z, ph2))));
    ph3 = fmaf(x.x, va.w, fmaf(x.y, vb.w, fmaf(x.z, vc.w, fmaf(x.w, vd.w, ph3))));
  }
#pragma unroll
  for (int off = 1; off <= 2; off <<= 1) {
    ph0 += __shfl_xor(ph0, off, 64);
    ph1 += __shfl_xor(ph1, off, 64);
    ph2 += __shfl_xor(ph2, off, 64);
    ph3 += __shfl_xor(ph3, off, 64);
  }
  float pe = (part == 0) ? ph0 : (part == 1) ? ph1 : (part == 2) ? ph2 : ph3;
  float a = asrc[s * NH + part] + adst[t * NH + part] + pe;
  a = (a > 0.f) ? a : SLOPE * a;
  araw[(size_t)posmap[e] * NH + part] = a;
}

__global__ __launch_bounds__(256) void k_gather(
    const float* __restrict__ xh, const float* __restrict__ araw,
    const int* __restrict__ csr_src, const int* __restrict__ offs,
    const float* __restrict__ asrc, const float* __restrict__ adst,
    const float* __restrict__ cb, const float* __restrict__ g,
    const float* __restrict__ bln, float* __restrict__ nf) {
  int t = blockIdx.x * 4 + (threadIdx.x >> 6);
  int d = threadIdx.x & 63;
  if (t >= NN) return;
  int h = d >> 4;
  int o0 = offs[t], o1 = offs[t + 1];
  int deg = o1 - o0;

  float m0 = -INFINITY, m1 = -INFINITY, m2 = -INFINITY, m3 = -INFINITY;
  for (int base = 0; base < deg; base += 64) {
    int j = base + d;
    if (j < deg) {
      float4 a = *(const float4*)(araw + (size_t)(o0 + j) * NH);
      m0 = fmaxf(m0, a.x); m1 = fmaxf(m1, a.y);
      m2 = fmaxf(m2, a.z); m3 = fmaxf(m3, a.w);
    }
  }
#pragma unroll
  for (int off = 32; off >= 1; off >>= 1) {
    m0 = fmaxf(m0, __shfl_xor(m0, off, 64));
    m1 = fmaxf(m1, __shfl_xor(m1, off, 64));
    m2 = fmaxf(m2, __shfl_xor(m2, off, 64));
    m3 = fmaxf(m3, __shfl_xor(m3, off, 64));
  }
  float sh = asrc[t * NH + h] + adst[t * NH + h];
  sh = (sh > 0.f) ? sh : SLOPE * sh;
  float mh = (h == 0) ? m0 : (h == 1) ? m1 : (h == 2) ? m2 : m3;
  mh = fmaxf(mh, sh);

  float acc = 0.f, wsum = 0.f;
  int j = 0;
  for (; j + 1 < deg; j += 2) {
    int sp0 = csr_src[o0 + j], sp1 = csr_src[o0 + j + 1];
    float ar0 = araw[(size_t)(o0 + j) * NH + h];
    float ar1 = araw[(size_t)(o0 + j + 1) * NH + h];
    float w0 = expf(ar0 - mh), w1 = expf(ar1 - mh);
    acc = fmaf(w0, xh[(size_t)sp0 * DD + d], acc);
    acc = fmaf(w1, xh[(size_t)sp1 * DD + d], acc);
    wsum += w0 + w1;
  }
  if (j < deg) {
    int sp = csr_src[o0 + j];
    float ar = araw[(size_t)(o0 + j) * NH + h];
    float w = expf(ar - mh);
    acc = fmaf(w, xh[(size_t)sp * DD + d], acc);
    wsum += w;
  }
  float wself = expf(sh - mh);
  acc = fmaf(wself, xh[(size_t)t * DD + d], acc);
  wsum += wself;

  float val = acc / (wsum + 1e-16f) + cb[d];
  float m = val;
#pragma unroll
  for (int off = 32; off >= 1; off >>= 1) m += __shfl_xor(m, off, 64);
  m *= (1.f / 64.f);
  float c = val - m;
  float q = c * c;
#pragma unroll
  for (int off = 32; off >= 1; off >>= 1) q += __shfl_xor(q, off, 64);
  float rstd = 1.f / sqrtf(q * (1.f / 64.f) + 1e-5f);
  float y = c * rstd * g[d] + bln[d];
  y = fmaxf(y, 0.f);
  nf[(size_t)t * DD + d] = y + nf[(size_t)t * DD + d];
}

// ---------------- edge MLP v3: 128 edges, 8 waves (2 rg x 4 cg) ---------------
// GEMM1: wave = rows rg*64..+63 (rt=0..3) x cols cg*48..+47 (t=0..2).
//   X single-bf16 in LDS; W1 hi/lo staged per K-slice in LDS (shared).
//   Each B-frag load feeds 8 MFMA (4rt x 2 split).
// LN cross-cg via 4KB P buffer. H overwrites X. GEMM2: cols cg*16..+15.
// Residual read fp32 from global ef (each (row,col) by exactly one lane).
__global__ __launch_bounds__(512, 4) void k_edge_mlp3(
    const float* __restrict__ nf, float* __restrict__ ef,
    const int* __restrict__ src, const int* __restrict__ dst,
    const __bf16* __restrict__ W1H, const __bf16* __restrict__ W1L,
    const float* __restrict__ b1, const float* __restrict__ g,
    const float* __restrict__ bg,
    const __bf16* __restrict__ W2H, const __bf16* __restrict__ W2L,
    const float* __restrict__ b2) {
  __shared__ __bf16 XH[EB * XSTR];      // 51200 B: X during GEMM1, H after
  __shared__ __bf16 Wbuf[24 * 512];     // 24576 B: staged W K-slice
  __shared__ float P[EB * 8];           // 4096 B: LN partials
  int tid = threadIdx.x;
  int e0 = blockIdx.x * EB;

  // stage X = [nf[src] | nf[dst] | ef] as single bf16
  for (int idx = tid; idx < EB * 48; idx += 512) {
    int row = idx / 48, q = idx % 48;
    const float4* sp;
    if (q < 16)      sp = (const float4*)(nf + (size_t)src[e0 + row] * DD) + q;
    else if (q < 32) sp = (const float4*)(nf + (size_t)dst[e0 + row] * DD) + (q - 16);
    else             sp = (const float4*)(ef + (size_t)(e0 + row) * DD) + (q - 32);
    float4 v = *sp;
    bf4 hv;
    hv[0] = (__bf16)v.x; hv[1] = (__bf16)v.y;
    hv[2] = (__bf16)v.z; hv[3] = (__bf16)v.w;
    *(bf4*)&XH[row * XSTR + q * 4] = hv;
  }
  __syncthreads();

  int w = tid >> 6, l = tid & 63;
  int rg = w >> 2, cg = w & 3;
  int gq = l >> 4, i = l & 15;

  f32x4 acc[4][3];
#pragma unroll
  for (int rt = 0; rt < 4; ++rt)
#pragma unroll
    for (int t = 0; t < 3; ++t) acc[rt][t] = (f32x4){0.f, 0.f, 0.f, 0.f};

  for (int s = 0; s < 6; ++s) {
    // stage W1 K-slice: 24 tiles (12t x hi/lo); wave w stages tiles w, w+8, w+16
#pragma unroll
    for (int q = w; q < 24; q += 8) {
      int t = q >> 1;
      const float4* gsrc =
          (const float4*)(((q & 1) ? W1L : W1H) + (size_t)(t * 6 + s) * 512) + l;
      float4 v = *gsrc;
      *(float4*)&Wbuf[q * 512 + l * 8] = v;
    }
    // A-frags for this K-slice (reads stable X region)
    bf8 a[4];
#pragma unroll
    for (int rt = 0; rt < 4; ++rt)
      a[rt] = *(const bf8*)&XH[(rg * 64 + rt * 16 + i) * XSTR + s * 32 + gq * 8];
    __syncthreads();
#pragma unroll
    for (int t = 0; t < 3; ++t) {
      int ti = cg * 3 + t;
      bf8 bh = *(const bf8*)&Wbuf[(ti * 2 + 0) * 512 + l * 8];
      bf8 bl = *(const bf8*)&Wbuf[(ti * 2 + 1) * 512 + l * 8];
#pragma unroll
      for (int rt = 0; rt < 4; ++rt) {
        acc[rt][t] = MFMA(a[rt], bh, acc[rt][t]);
        acc[rt][t] = MFMA(a[rt], bl, acc[rt][t]);
      }
    }
    __syncthreads();
  }

  // bias + LN partials (this wave covers 48 of 192 cols per row)
  float b1v[3], gv[3], bgv[3];
#pragma unroll
  for (int t = 0; t < 3; ++t) {
    int n = cg * 48 + t * 16 + i;
    b1v[t] = b1[n]; gv[t] = g[n]; bgv[t] = bg[n];
  }
#pragma unroll
  for (int rt = 0; rt < 4; ++rt)
#pragma unroll
    for (int t = 0; t < 3; ++t)
#pragma unroll
      for (int r = 0; r < 4; ++r) acc[rt][t][r] += b1v[t];

#pragma unroll
  for (int rt = 0; rt < 4; ++rt)
#pragma unroll
    for (int r = 0; r < 4; ++r) {
      float sm = 0.f, sq = 0.f;
#pragma unroll
      for (int t = 0; t < 3; ++t) { float x = acc[rt][t][r]; sm += x; sq = fmaf(x, x, sq); }
#pragma unroll
      for (int off = 1; off <= 8; off <<= 1) {
        sm += __shfl_xor(sm, off, 64);
        sq += __shfl_xor(sq, off, 64);
      }
      if (i == 0) {
        int row = rg * 64 + rt * 16 + gq * 4 + r;
        P[row * 8 + cg * 2]     = sm;
        P[row * 8 + cg * 2 + 1] = sq;
      }
    }
  __syncthreads();

  // finalize LN, relu, write H over X (all GEMM1 X-reads completed above)
#pragma unroll
  for (int rt = 0; rt < 4; ++rt)
#pragma unroll
    for (int r = 0; r < 4; ++r) {
      int row = rg * 64 + rt * 16 + gq * 4 + r;
      float4 p0 = *(const float4*)&P[row * 8];
      float4 p1 = *(const float4*)&P[row * 8 + 4];
      float sm = p0.x + p0.z + p1.x + p1.z;
      float sq = p0.y + p0.w + p1.y + p1.w;
      float mean = sm * (1.f / (float)DIN);
      float var = sq * (1.f / (float)DIN) - mean * mean;
      float rstd = 1.f / sqrtf(var + 1e-5f);
#pragma unroll
      for (int t = 0; t < 3; ++t) {
        float y = (acc[rt][t][r] - mean) * rstd * gv[t] + bgv[t];
        y = fmaxf(y, 0.f);
        XH[row * XSTR + cg * 48 + t * 16 + i] = (__bf16)y;
      }
    }
  __syncthreads();

  // GEMM2: wave = rows rg*64..+63 x cols cg*16..+15; W2 hi/lo staged per K-slice
  f32x4 acc2[4];
#pragma unroll
  for (int rt = 0; rt < 4; ++rt) acc2[rt] = (f32x4){0.f, 0.f, 0.f, 0.f};

  for (int s = 0; s < 6; ++s) {
    // 8 tiles (4t x hi/lo); wave w stages tile w
    {
      int t = w >> 1;
      const float4* gsrc =
          (const float4*)(((w & 1) ? W2L : W2H) + (size_t)(t * 6 + s) * 512) + l;
      float4 v = *gsrc;
      *(float4*)&Wbuf[w * 512 + l * 8] = v;
    }
    bf8 a2[4];
#pragma unroll
    for (int rt = 0; rt < 4; ++rt)
      a2[rt] = *(const bf8*)&XH[(rg * 64 + rt * 16 + i) * XSTR + s * 32 + gq * 8];
    __syncthreads();
    bf8 bh = *(const bf8*)&Wbuf[(cg * 2 + 0) * 512 + l * 8];
    bf8 bl = *(const bf8*)&Wbuf[(cg * 2 + 1) * 512 + l * 8];
#pragma unroll
    for (int rt = 0; rt < 4; ++rt) {
      acc2[rt] = MFMA(a2[rt], bh, acc2[rt]);
      acc2[rt] = MFMA(a2[rt], bl, acc2[rt]);
    }
    __syncthreads();
  }

  float b2v = b2[cg * 16 + i];
  int col = cg * 16 + i;
#pragma unroll
  for (int rt = 0; rt < 4; ++rt)
#pragma unroll
    for (int r = 0; r < 4; ++r) {
      int row = rg * 64 + rt * 16 + gq * 4 + r;
      float res = ef[(size_t)(e0 + row) * DD + col];   // original ef, fp32
      ef[(size_t)(e0 + row) * DD + col] = acc2[rt][r] + b2v + res;
    }
}

extern "C" void kernel_launch(void* const* d_in, const int* in_sizes, int n_in,
                              void* d_out, int out_size, void* d_ws, size_t ws_size,
                              hipStream_t stream) {
  const float* node_feats = (const float*)d_in[0];
  const float* edge_feats = (const float*)d_in[1];
  const int*   edge_index = (const int*)d_in[2];
  const float* conv_w  = (const float*)d_in[3];
  const float* att_src = (const float*)d_in[4];
  const float* att_dst = (const float*)d_in[5];
  const float* edge_w  = (const float*)d_in[6];
  const float* att_edge= (const float*)d_in[7];
  const float* conv_b  = (const float*)d_in[8];
  const float* ln_g    = (const float*)d_in[9];
  const float* ln_b    = (const float*)d_in[10];
  const float* up1_w   = (const float*)d_in[11];
  const float* up1_b   = (const float*)d_in[12];
  const float* up_ln_g = (const float*)d_in[13];
  const float* up_ln_b = (const float*)d_in[14];
  const float* up2_w   = (const float*)d_in[15];
  const float* up2_b   = (const float*)d_in[16];

  const int* src = edge_index;
  const int* dst = edge_index + NE;

  float* nf = (float*)d_out;
  float* ef = nf + (size_t)NN * DD;

  float* w = (float*)d_ws;
  float* xh    = w; w += (size_t)NN * DD;
  float* asrc  = w; w += (size_t)NN * NH;
  float* adst  = w; w += (size_t)NN * NH;
  float* araw  = w; w += (size_t)NE * NH;
  float* vbuf  = w; w += 256;
  __bf16* W1H = (__bf16*)w; w += (size_t)4 * 36864 / 2;
  __bf16* W1L = (__bf16*)w; w += (size_t)4 * 36864 / 2;
  __bf16* W2H = (__bf16*)w; w += (size_t)4 * 12288 / 2;
  __bf16* W2L = (__bf16*)w; w += (size_t)4 * 12288 / 2;
  int* deg     = (int*)w; w += NN;
  int* offs    = (int*)w; w += NN + 1;
  int* cursor  = (int*)w; w += NN;
  int* bsum    = (int*)w; w += 128;
  int* boff    = (int*)w; w += 128;
  int* csr_src = (int*)w; w += NE;
  int* posmap  = (int*)w; w += NE;

  hipMemcpyAsync(nf, node_feats, (size_t)NN * DD * sizeof(float),
                 hipMemcpyDeviceToDevice, stream);
  hipMemcpyAsync(ef, edge_feats, (size_t)NE * DD * sizeof(float),
                 hipMemcpyDeviceToDevice, stream);

  k_pack_w1<<<72, 256, 0, stream>>>(up1_w, W1H, W1L);
  k_pack_w2<<<24, 256, 0, stream>>>(up2_w, W2H, W2L);

  const int nb = (NN + 1023) / 1024;
  k_zero<<<(NN + 255) / 256, 256, 0, stream>>>(deg);
  k_hist<<<(NE + 255) / 256, 256, 0, stream>>>(dst, deg);
  k_scan1<<<nb, 256, 0, stream>>>(deg, offs, bsum);
  k_scan2<<<1, 64, 0, stream>>>(bsum, boff, offs, nb);
  k_scan3<<<(NN + 255) / 256, 256, 0, stream>>>(offs, boff, cursor);
  k_scatter<<<(NE + 255) / 256, 256, 0, stream>>>(src, dst, cursor, csr_src, posmap);

  for (int l = 0; l < NL; ++l) {
    k_compute_v<<<1, 256, 0, stream>>>(edge_w + (size_t)l * DD * DD,
                                       att_edge + (size_t)l * NH * NC, vbuf);
    k_xh<<<NN / 4, 256, 0, stream>>>(nf, conv_w + (size_t)l * DD * DD,
                                     att_src + (size_t)l * NH * NC,
                                     att_dst + (size_t)l * NH * NC, xh, asrc, adst);
    k_pass1<<<NE / 64, 256, 0, stream>>>(ef, src, dst, vbuf, asrc, adst, posmap, araw);
    k_gather<<<NN / 4, 256, 0, stream>>>(xh, araw, csr_src, offs, asrc, adst,
                                         conv_b + (size_t)l * DD,
                                         ln_g + (size_t)l * DD,
                                         ln_b + (size_t)l * DD, nf);
    k_edge_mlp3<<<NE / EB, 512, 0, stream>>>(
        nf, ef, src, dst,
        W1H + (size_t)l * 36864, W1L + (size_t)l * 36864,
        up1_b + (size_t)l * DIN,
        up_ln_g + (size_t)l * DIN, up_ln_b + (size_t)l * DIN,
        W2H + (size_t)l * 12288, W2L + (size_t)l * 12288,
        up2_b + (size_t)l * DD);
  }
}

// Round 7
// 4667.858 us; speedup vs baseline: 2.8563x; 1.2837x over previous
//
#include <hip/hip_runtime.h>
#include <math.h>

#define NN 100000
#define NE 1600000
#define DD 64
#define NL 4
#define NH 4
#define NC 16
#define DIN 192
#define SLOPE 0.2f
#define EB 128
#define XSTR 200

typedef __bf16 bf8 __attribute__((ext_vector_type(8)));
typedef __bf16 bf4 __attribute__((ext_vector_type(4)));
typedef float f32x4 __attribute__((ext_vector_type(4)));

__device__ __forceinline__ f32x4 MFMA(bf8 a, bf8 b, f32x4 c) {
  return __builtin_amdgcn_mfma_f32_16x16x32_bf16(a, b, c, 0, 0, 0);
}

// ---------------- weight packing: separate hi/lo planes, 1KB tiles -----------
// tile (t,s): lane l holds W[k][n], k=s*32+(l>>4)*8+j, n=t*16+(l&15), j=0..7
__global__ void k_pack_w1(const float* __restrict__ W1, __bf16* __restrict__ WH,
                          __bf16* __restrict__ WL) {
  int gidx = blockIdx.x * 256 + threadIdx.x;
  if (gidx >= 4 * 4608) return;
  int lyr = gidx / 4608, rem = gidx % 4608;
  int lane = rem & 63, ts = rem >> 6;
  int s = ts % 6, t = ts / 6;
  const float* Wl = W1 + (size_t)lyr * DIN * DIN;
  size_t base = (size_t)lyr * 36864 + ((size_t)(t * 6 + s) * 64 + lane) * 8;
  int k0 = s * 32 + (lane >> 4) * 8, n = t * 16 + (lane & 15);
#pragma unroll
  for (int j = 0; j < 8; ++j) {
    float v = Wl[(size_t)(k0 + j) * DIN + n];
    __bf16 h = (__bf16)v;
    WH[base + j] = h;
    WL[base + j] = (__bf16)(v - (float)h);
  }
}

__global__ void k_pack_w2(const float* __restrict__ W2, __bf16* __restrict__ WH,
                          __bf16* __restrict__ WL) {
  int gidx = blockIdx.x * 256 + threadIdx.x;
  if (gidx >= 4 * 1536) return;
  int lyr = gidx / 1536, rem = gidx % 1536;
  int lane = rem & 63, ts = rem >> 6;
  int s = ts % 6, t = ts / 6;
  const float* Wl = W2 + (size_t)lyr * DIN * DD;
  size_t base = (size_t)lyr * 12288 + ((size_t)(t * 6 + s) * 64 + lane) * 8;
  int k0 = s * 32 + (lane >> 4) * 8, n = t * 16 + (lane & 15);
#pragma unroll
  for (int j = 0; j < 8; ++j) {
    float v = Wl[(size_t)(k0 + j) * DD + n];
    __bf16 h = (__bf16)v;
    WH[base + j] = h;
    WL[base + j] = (__bf16)(v - (float)h);
  }
}

// ---------------- CSR build (once per launch; graph is static) ----------------
__global__ void k_zero(int* __restrict__ deg) {
  int i = blockIdx.x * 256 + threadIdx.x;
  if (i < NN) deg[i] = 0;
}

__global__ void k_hist(const int* __restrict__ dst, int* __restrict__ deg) {
  int e = blockIdx.x * 256 + threadIdx.x;
  if (e < NE) atomicAdd(&deg[dst[e]], 1);
}

__global__ void k_scan1(const int* __restrict__ deg, int* __restrict__ offs,
                        int* __restrict__ bsum) {
  __shared__ int sh[256];
  int t = threadIdx.x, b = blockIdx.x;
  int i0 = b * 1024 + t * 4;
  int d0 = (i0 + 0 < NN) ? deg[i0 + 0] : 0;
  int d1 = (i0 + 1 < NN) ? deg[i0 + 1] : 0;
  int d2 = (i0 + 2 < NN) ? deg[i0 + 2] : 0;
  int d3 = (i0 + 3 < NN) ? deg[i0 + 3] : 0;
  int s4 = d0 + d1 + d2 + d3;
  sh[t] = s4;
  __syncthreads();
  int p = 0;
#pragma unroll
  for (int off = 1; off < 256; off <<= 1) {
    int v = (t >= off) ? sh[t - off] : 0;
    __syncthreads();
    sh[t] += v;
    __syncthreads();
  }
  p = sh[t] - s4;
  if (t == 255) bsum[b] = sh[255];
  if (i0 + 0 < NN) offs[i0 + 0] = p;
  if (i0 + 1 < NN) offs[i0 + 1] = p + d0;
  if (i0 + 2 < NN) offs[i0 + 2] = p + d0 + d1;
  if (i0 + 3 < NN) offs[i0 + 3] = p + d0 + d1 + d2;
}

__global__ void k_scan2(int* __restrict__ bsum, int* __restrict__ boff,
                        int* __restrict__ offs, int nb) {
  if (threadIdx.x == 0 && blockIdx.x == 0) {
    int run = 0;
    for (int k = 0; k < nb; ++k) { boff[k] = run; run += bsum[k]; }
    offs[NN] = NE;
  }
}

__global__ void k_scan3(int* __restrict__ offs, const int* __restrict__ boff,
                        int* __restrict__ cursor) {
  int i = blockIdx.x * 256 + threadIdx.x;
  if (i < NN) {
    int v = offs[i] + boff[i >> 10];
    offs[i] = v;
    cursor[i] = v;
  }
}

__global__ void k_scatter(const int* __restrict__ src, const int* __restrict__ dst,
                          int* __restrict__ cursor, int* __restrict__ csr_src,
                          int* __restrict__ posmap) {
  int e = blockIdx.x * 256 + threadIdx.x;
  if (e >= NE) return;
  int pos = atomicAdd(&cursor[dst[e]], 1);
  csr_src[pos] = src[e];
  posmap[e] = pos;
}

// ---------------- GAT conv path ----------------
__global__ void k_compute_v(const float* __restrict__ ew, const float* __restrict__ ae,
                            float* __restrict__ v) {
  int d = threadIdx.x >> 2, h = threadIdx.x & 3;
  float s = 0.f;
#pragma unroll
  for (int c = 0; c < NC; ++c) s = fmaf(ew[d * DD + h * NC + c], ae[h * NC + c], s);
  v[d * NH + h] = s;
}

__global__ void k_xh(const float* __restrict__ nf, const float* __restrict__ W,
                     const float* __restrict__ as_, const float* __restrict__ ad_,
                     float* __restrict__ xh, float* __restrict__ asrc,
                     float* __restrict__ adst) {
  int t = blockIdx.x * 4 + (threadIdx.x >> 6);
  int d = threadIdx.x & 63;
  if (t >= NN) return;
  const float* x = nf + (size_t)t * DD;
  float acc = 0.f;
#pragma unroll
  for (int k = 0; k < DD; ++k) acc = fmaf(x[k], W[k * DD + d], acc);
  xh[(size_t)t * DD + d] = acc;
  int h = d >> 4, c = d & 15;
  float ps = acc * as_[h * NC + c];
  float pd = acc * ad_[h * NC + c];
#pragma unroll
  for (int off = 8; off >= 1; off >>= 1) {
    ps += __shfl_xor(ps, off, 64);
    pd += __shfl_xor(pd, off, 64);
  }
  if (c == 0) { asrc[t * NH + h] = ps; adst[t * NH + h] = pd; }
}

__global__ void k_pass1(const float* __restrict__ ef, const int* __restrict__ src,
                        const int* __restrict__ dst, const float* __restrict__ v,
                        const float* __restrict__ asrc, const float* __restrict__ adst,
                        const int* __restrict__ posmap, float* __restrict__ araw) {
  int e = blockIdx.x * 64 + (threadIdx.x >> 2);
  int part = threadIdx.x & 3;
  if (e >= NE) return;
  int s = src[e], t = dst[e];
  float ph0 = 0.f, ph1 = 0.f, ph2 = 0.f, ph3 = 0.f;
  const float4* ep = (const float4*)(ef + (size_t)e * DD + part * 16);
  const float4* v4 = (const float4*)v;
#pragma unroll
  for (int c4 = 0; c4 < 4; ++c4) {
    float4 x = ep[c4];
    int d0 = part * 16 + c4 * 4;
    float4 va = v4[d0], vb = v4[d0 + 1], vc = v4[d0 + 2], vd = v4[d0 + 3];
    ph0 = fmaf(x.x, va.x, fmaf(x.y, vb.x, fmaf(x.z, vc.x, fmaf(x.w, vd.x, ph0))));
    ph1 = fmaf(x.x, va.y, fmaf(x.y, vb.y, fmaf(x.z, vc.y, fmaf(x.w, vd.y, ph1))));
    ph2 = fmaf(x.x, va.z, fmaf(x.y, vb.z, fmaf(x.z, vc.z, fmaf(x.w, vd.z, ph2))));
    ph3 = fmaf(x.x, va.w, fmaf(x.y, vb.w, fmaf(x.z, vc.w, fmaf(x.w, vd.w, ph3))));
  }
#pragma unroll
  for (int off = 1; off <= 2; off <<= 1) {
    ph0 += __shfl_xor(ph0, off, 64);
    ph1 += __shfl_xor(ph1, off, 64);
    ph2 += __shfl_xor(ph2, off, 64);
    ph3 += __shfl_xor(ph3, off, 64);
  }
  float pe = (part == 0) ? ph0 : (part == 1) ? ph1 : (part == 2) ? ph2 : ph3;
  float a = asrc[s * NH + part] + adst[t * NH + part] + pe;
  a = (a > 0.f) ? a : SLOPE * a;
  araw[(size_t)posmap[e] * NH + part] = a;
}

__global__ __launch_bounds__(256) void k_gather(
    const float* __restrict__ xh, const float* __restrict__ araw,
    const int* __restrict__ csr_src, const int* __restrict__ offs,
    const float* __restrict__ asrc, const float* __restrict__ adst,
    const float* __restrict__ cb, const float* __restrict__ g,
    const float* __restrict__ bln, float* __restrict__ nf) {
  int t = blockIdx.x * 4 + (threadIdx.x >> 6);
  int d = threadIdx.x & 63;
  if (t >= NN) return;
  int h = d >> 4;
  int o0 = offs[t], o1 = offs[t + 1];
  int deg = o1 - o0;

  float m0 = -INFINITY, m1 = -INFINITY, m2 = -INFINITY, m3 = -INFINITY;
  for (int base = 0; base < deg; base += 64) {
    int j = base + d;
    if (j < deg) {
      float4 a = *(const float4*)(araw + (size_t)(o0 + j) * NH);
      m0 = fmaxf(m0, a.x); m1 = fmaxf(m1, a.y);
      m2 = fmaxf(m2, a.z); m3 = fmaxf(m3, a.w);
    }
  }
#pragma unroll
  for (int off = 32; off >= 1; off >>= 1) {
    m0 = fmaxf(m0, __shfl_xor(m0, off, 64));
    m1 = fmaxf(m1, __shfl_xor(m1, off, 64));
    m2 = fmaxf(m2, __shfl_xor(m2, off, 64));
    m3 = fmaxf(m3, __shfl_xor(m3, off, 64));
  }
  float sh = asrc[t * NH + h] + adst[t * NH + h];
  sh = (sh > 0.f) ? sh : SLOPE * sh;
  float mh = (h == 0) ? m0 : (h == 1) ? m1 : (h == 2) ? m2 : m3;
  mh = fmaxf(mh, sh);

  float acc = 0.f, wsum = 0.f;
  int j = 0;
  for (; j + 1 < deg; j += 2) {
    int sp0 = csr_src[o0 + j], sp1 = csr_src[o0 + j + 1];
    float ar0 = araw[(size_t)(o0 + j) * NH + h];
    float ar1 = araw[(size_t)(o0 + j + 1) * NH + h];
    float w0 = expf(ar0 - mh), w1 = expf(ar1 - mh);
    acc = fmaf(w0, xh[(size_t)sp0 * DD + d], acc);
    acc = fmaf(w1, xh[(size_t)sp1 * DD + d], acc);
    wsum += w0 + w1;
  }
  if (j < deg) {
    int sp = csr_src[o0 + j];
    float ar = araw[(size_t)(o0 + j) * NH + h];
    float w = expf(ar - mh);
    acc = fmaf(w, xh[(size_t)sp * DD + d], acc);
    wsum += w;
  }
  float wself = expf(sh - mh);
  acc = fmaf(wself, xh[(size_t)t * DD + d], acc);
  wsum += wself;

  float val = acc / (wsum + 1e-16f) + cb[d];
  float m = val;
#pragma unroll
  for (int off = 32; off >= 1; off >>= 1) m += __shfl_xor(m, off, 64);
  m *= (1.f / 64.f);
  float c = val - m;
  float q = c * c;
#pragma unroll
  for (int off = 32; off >= 1; off >>= 1) q += __shfl_xor(q, off, 64);
  float rstd = 1.f / sqrtf(q * (1.f / 64.f) + 1e-5f);
  float y = c * rstd * g[d] + bln[d];
  y = fmaxf(y, 0.f);
  nf[(size_t)t * DD + d] = y + nf[(size_t)t * DD + d];
}

// ---------------- edge MLP v4: B direct from global (L2), zero K-loop barriers
// 128 edges/block, 8 waves (2 rg x 4 cg). Wave: rows rg*64+rt*16 (rt 0..3),
// GEMM1 cols cg*48+t*16 (t 0..2), GEMM2 cols cg*16. X single-bf16 in LDS
// (reused as H); W hi/lo read per-wave straight from L2-resident packed planes.
__global__ __launch_bounds__(512, 4) void k_edge_mlp4(
    const float* __restrict__ nf, float* __restrict__ ef,
    const int* __restrict__ src, const int* __restrict__ dst,
    const __bf16* __restrict__ W1H, const __bf16* __restrict__ W1L,
    const float* __restrict__ b1, const float* __restrict__ g,
    const float* __restrict__ bg,
    const __bf16* __restrict__ W2H, const __bf16* __restrict__ W2L,
    const float* __restrict__ b2) {
  __shared__ __bf16 XH[EB * XSTR];   // 51200 B: X during GEMM1, H after
  __shared__ float P[EB * 8];        // 4096 B: LN partials
  int tid = threadIdx.x;
  int e0 = blockIdx.x * EB;

  // stage X: thread owns row tid>>2; 12 float4 per thread (q = iter*4 + tid&3)
  {
    int row = tid >> 2;
    int se = src[e0 + row], de = dst[e0 + row];
    const float4* ps = (const float4*)(nf + (size_t)se * DD);
    const float4* pd = (const float4*)(nf + (size_t)de * DD);
    const float4* pe = (const float4*)(ef + (size_t)(e0 + row) * DD);
#pragma unroll
    for (int it = 0; it < 12; ++it) {
      int q = it * 4 + (tid & 3);
      float4 v = (q < 16) ? ps[q] : (q < 32) ? pd[q - 16] : pe[q - 32];
      bf4 hv;
      hv[0] = (__bf16)v.x; hv[1] = (__bf16)v.y;
      hv[2] = (__bf16)v.z; hv[3] = (__bf16)v.w;
      *(bf4*)&XH[row * XSTR + q * 4] = hv;
    }
  }
  __syncthreads();

  int w = tid >> 6, l = tid & 63;
  int rg = w >> 2, cg = w & 3;
  int gq = l >> 4, i = l & 15;

  f32x4 acc[4][3];
#pragma unroll
  for (int rt = 0; rt < 4; ++rt)
#pragma unroll
    for (int t = 0; t < 3; ++t) acc[rt][t] = (f32x4){0.f, 0.f, 0.f, 0.f};

  // GEMM1: no barriers; B-tiles from global (coalesced 1KB/wave, L2-hot)
#pragma unroll
  for (int s = 0; s < 6; ++s) {
    bf8 a[4];
#pragma unroll
    for (int rt = 0; rt < 4; ++rt)
      a[rt] = *(const bf8*)&XH[(rg * 64 + rt * 16 + i) * XSTR + s * 32 + gq * 8];
#pragma unroll
    for (int t = 0; t < 3; ++t) {
      size_t tb = ((size_t)((cg * 3 + t) * 6 + s) * 64 + l) * 8;
      bf8 bh = *(const bf8*)(W1H + tb);
      bf8 bl = *(const bf8*)(W1L + tb);
#pragma unroll
      for (int rt = 0; rt < 4; ++rt) {
        acc[rt][t] = MFMA(a[rt], bh, acc[rt][t]);
        acc[rt][t] = MFMA(a[rt], bl, acc[rt][t]);
      }
    }
  }

  // bias + LN partials (this wave covers 48 of 192 cols per row)
  float b1v[3], gv[3], bgv[3];
#pragma unroll
  for (int t = 0; t < 3; ++t) {
    int n = cg * 48 + t * 16 + i;
    b1v[t] = b1[n]; gv[t] = g[n]; bgv[t] = bg[n];
  }
#pragma unroll
  for (int rt = 0; rt < 4; ++rt)
#pragma unroll
    for (int t = 0; t < 3; ++t)
#pragma unroll
      for (int r = 0; r < 4; ++r) acc[rt][t][r] += b1v[t];

#pragma unroll
  for (int rt = 0; rt < 4; ++rt)
#pragma unroll
    for (int r = 0; r < 4; ++r) {
      float sm = 0.f, sq = 0.f;
#pragma unroll
      for (int t = 0; t < 3; ++t) { float x = acc[rt][t][r]; sm += x; sq = fmaf(x, x, sq); }
#pragma unroll
      for (int off = 1; off <= 8; off <<= 1) {
        sm += __shfl_xor(sm, off, 64);
        sq += __shfl_xor(sq, off, 64);
      }
      if (i == 0) {
        int row = rg * 64 + rt * 16 + gq * 4 + r;
        P[row * 8 + cg * 2]     = sm;
        P[row * 8 + cg * 2 + 1] = sq;
      }
    }
  __syncthreads();   // barrier 1: P ready AND all GEMM1 X-reads done

  // finalize LN, relu, write H over X
#pragma unroll
  for (int rt = 0; rt < 4; ++rt)
#pragma unroll
    for (int r = 0; r < 4; ++r) {
      int row = rg * 64 + rt * 16 + gq * 4 + r;
      float4 p0 = *(const float4*)&P[row * 8];
      float4 p1 = *(const float4*)&P[row * 8 + 4];
      float sm = p0.x + p0.z + p1.x + p1.z;
      float sq = p0.y + p0.w + p1.y + p1.w;
      float mean = sm * (1.f / (float)DIN);
      float var = sq * (1.f / (float)DIN) - mean * mean;
      float rstd = 1.f / sqrtf(var + 1e-5f);
#pragma unroll
      for (int t = 0; t < 3; ++t) {
        float y = (acc[rt][t][r] - mean) * rstd * gv[t] + bgv[t];
        y = fmaxf(y, 0.f);
        XH[row * XSTR + cg * 48 + t * 16 + i] = (__bf16)y;
      }
    }
  __syncthreads();   // barrier 2: H fully published

  // GEMM2: no barriers; W2 tiles from global
  f32x4 acc2[4];
#pragma unroll
  for (int rt = 0; rt < 4; ++rt) acc2[rt] = (f32x4){0.f, 0.f, 0.f, 0.f};

#pragma unroll
  for (int s = 0; s < 6; ++s) {
    bf8 a2[4];
#pragma unroll
    for (int rt = 0; rt < 4; ++rt)
      a2[rt] = *(const bf8*)&XH[(rg * 64 + rt * 16 + i) * XSTR + s * 32 + gq * 8];
    size_t tb = ((size_t)(cg * 6 + s) * 64 + l) * 8;
    bf8 bh = *(const bf8*)(W2H + tb);
    bf8 bl = *(const bf8*)(W2L + tb);
#pragma unroll
    for (int rt = 0; rt < 4; ++rt) {
      acc2[rt] = MFMA(a2[rt], bh, acc2[rt]);
      acc2[rt] = MFMA(a2[rt], bl, acc2[rt]);
    }
  }

  float b2v = b2[cg * 16 + i];
  int col = cg * 16 + i;
#pragma unroll
  for (int rt = 0; rt < 4; ++rt)
#pragma unroll
    for (int r = 0; r < 4; ++r) {
      int row = rg * 64 + rt * 16 + gq * 4 + r;
      float res = ef[(size_t)(e0 + row) * DD + col];   // original ef, fp32
      ef[(size_t)(e0 + row) * DD + col] = acc2[rt][r] + b2v + res;
    }
}

extern "C" void kernel_launch(void* const* d_in, const int* in_sizes, int n_in,
                              void* d_out, int out_size, void* d_ws, size_t ws_size,
                              hipStream_t stream) {
  const float* node_feats = (const float*)d_in[0];
  const float* edge_feats = (const float*)d_in[1];
  const int*   edge_index = (const int*)d_in[2];
  const float* conv_w  = (const float*)d_in[3];
  const float* att_src = (const float*)d_in[4];
  const float* att_dst = (const float*)d_in[5];
  const float* edge_w  = (const float*)d_in[6];
  const float* att_edge= (const float*)d_in[7];
  const float* conv_b  = (const float*)d_in[8];
  const float* ln_g    = (const float*)d_in[9];
  const float* ln_b    = (const float*)d_in[10];
  const float* up1_w   = (const float*)d_in[11];
  const float* up1_b   = (const float*)d_in[12];
  const float* up_ln_g = (const float*)d_in[13];
  const float* up_ln_b = (const float*)d_in[14];
  const float* up2_w   = (const float*)d_in[15];
  const float* up2_b   = (const float*)d_in[16];

  const int* src = edge_index;
  const int* dst = edge_index + NE;

  float* nf = (float*)d_out;
  float* ef = nf + (size_t)NN * DD;

  float* w = (float*)d_ws;
  float* xh    = w; w += (size_t)NN * DD;
  float* asrc  = w; w += (size_t)NN * NH;
  float* adst  = w; w += (size_t)NN * NH;
  float* araw  = w; w += (size_t)NE * NH;
  float* vbuf  = w; w += 256;
  __bf16* W1H = (__bf16*)w; w += (size_t)4 * 36864 / 2;
  __bf16* W1L = (__bf16*)w; w += (size_t)4 * 36864 / 2;
  __bf16* W2H = (__bf16*)w; w += (size_t)4 * 12288 / 2;
  __bf16* W2L = (__bf16*)w; w += (size_t)4 * 12288 / 2;
  int* deg     = (int*)w; w += NN;
  int* offs    = (int*)w; w += NN + 1;
  int* cursor  = (int*)w; w += NN;
  int* bsum    = (int*)w; w += 128;
  int* boff    = (int*)w; w += 128;
  int* csr_src = (int*)w; w += NE;
  int* posmap  = (int*)w; w += NE;

  hipMemcpyAsync(nf, node_feats, (size_t)NN * DD * sizeof(float),
                 hipMemcpyDeviceToDevice, stream);
  hipMemcpyAsync(ef, edge_feats, (size_t)NE * DD * sizeof(float),
                 hipMemcpyDeviceToDevice, stream);

  k_pack_w1<<<72, 256, 0, stream>>>(up1_w, W1H, W1L);
  k_pack_w2<<<24, 256, 0, stream>>>(up2_w, W2H, W2L);

  const int nb = (NN + 1023) / 1024;
  k_zero<<<(NN + 255) / 256, 256, 0, stream>>>(deg);
  k_hist<<<(NE + 255) / 256, 256, 0, stream>>>(dst, deg);
  k_scan1<<<nb, 256, 0, stream>>>(deg, offs, bsum);
  k_scan2<<<1, 64, 0, stream>>>(bsum, boff, offs, nb);
  k_scan3<<<(NN + 255) / 256, 256, 0, stream>>>(offs, boff, cursor);
  k_scatter<<<(NE + 255) / 256, 256, 0, stream>>>(src, dst, cursor, csr_src, posmap);

  for (int l = 0; l < NL; ++l) {
    k_compute_v<<<1, 256, 0, stream>>>(edge_w + (size_t)l * DD * DD,
                                       att_edge + (size_t)l * NH * NC, vbuf);
    k_xh<<<NN / 4, 256, 0, stream>>>(nf, conv_w + (size_t)l * DD * DD,
                                     att_src + (size_t)l * NH * NC,
                                     att_dst + (size_t)l * NH * NC, xh, asrc, adst);
    k_pass1<<<NE / 64, 256, 0, stream>>>(ef, src, dst, vbuf, asrc, adst, posmap, araw);
    k_gather<<<NN / 4, 256, 0, stream>>>(xh, araw, csr_src, offs, asrc, adst,
                                         conv_b + (size_t)l * DD,
                                         ln_g + (size_t)l * DD,
                                         ln_b + (size_t)l * DD, nf);
    k_edge_mlp4<<<NE / EB, 512, 0, stream>>>(
        nf, ef, src, dst,
        W1H + (size_t)l * 36864, W1L + (size_t)l * 36864,
        up1_b + (size_t)l * DIN,
        up_ln_g + (size_t)l * DIN, up_ln_b + (size_t)l * DIN,
        W2H + (size_t)l * 12288, W2L + (size_t)l * 12288,
        up2_b + (size_t)l * DD);
  }
}

// Round 8
// 3827.515 us; speedup vs baseline: 3.4834x; 1.2196x over previous
//
#include <hip/hip_runtime.h>
#include <math.h>

#define NN 100000
#define NE 1600000
#define DD 64
#define NL 4
#define NH 4
#define NC 16
#define DIN 192
#define SLOPE 0.2f
#define EB 128
#define XSTR 200

typedef __bf16 bf8 __attribute__((ext_vector_type(8)));
typedef __bf16 bf4 __attribute__((ext_vector_type(4)));
typedef __bf16 bf2 __attribute__((ext_vector_type(2)));
typedef float f32x4 __attribute__((ext_vector_type(4)));

__device__ __forceinline__ f32x4 MFMA(bf8 a, bf8 b, f32x4 c) {
  return __builtin_amdgcn_mfma_f32_16x16x32_bf16(a, b, c, 0, 0, 0);
}

// ---------------- weight packing: single bf16 plane, 1KB tiles ----------------
// tile (t,s): lane l holds W[k][n], k=s*32+(l>>4)*8+j, n=t*16+(l&15), j=0..7
__global__ void k_pack_w1(const float* __restrict__ W1, __bf16* __restrict__ WH) {
  int gidx = blockIdx.x * 256 + threadIdx.x;
  if (gidx >= 4 * 4608) return;
  int lyr = gidx / 4608, rem = gidx % 4608;
  int lane = rem & 63, ts = rem >> 6;
  int s = ts % 6, t = ts / 6;
  const float* Wl = W1 + (size_t)lyr * DIN * DIN;
  size_t base = (size_t)lyr * 36864 + ((size_t)(t * 6 + s) * 64 + lane) * 8;
  int k0 = s * 32 + (lane >> 4) * 8, n = t * 16 + (lane & 15);
#pragma unroll
  for (int j = 0; j < 8; ++j)
    WH[base + j] = (__bf16)Wl[(size_t)(k0 + j) * DIN + n];
}

__global__ void k_pack_w2(const float* __restrict__ W2, __bf16* __restrict__ WH) {
  int gidx = blockIdx.x * 256 + threadIdx.x;
  if (gidx >= 4 * 1536) return;
  int lyr = gidx / 1536, rem = gidx % 1536;
  int lane = rem & 63, ts = rem >> 6;
  int s = ts % 6, t = ts / 6;
  const float* Wl = W2 + (size_t)lyr * DIN * DD;
  size_t base = (size_t)lyr * 12288 + ((size_t)(t * 6 + s) * 64 + lane) * 8;
  int k0 = s * 32 + (lane >> 4) * 8, n = t * 16 + (lane & 15);
#pragma unroll
  for (int j = 0; j < 8; ++j)
    WH[base + j] = (__bf16)Wl[(size_t)(k0 + j) * DD + n];
}

// ---------------- CSR build (once per launch; graph is static) ----------------
__global__ void k_zero(int* __restrict__ deg) {
  int i = blockIdx.x * 256 + threadIdx.x;
  if (i < NN) deg[i] = 0;
}

__global__ void k_hist(const int* __restrict__ dst, int* __restrict__ deg) {
  int e = blockIdx.x * 256 + threadIdx.x;
  if (e < NE) atomicAdd(&deg[dst[e]], 1);
}

__global__ void k_scan1(const int* __restrict__ deg, int* __restrict__ offs,
                        int* __restrict__ bsum) {
  __shared__ int sh[256];
  int t = threadIdx.x, b = blockIdx.x;
  int i0 = b * 1024 + t * 4;
  int d0 = (i0 + 0 < NN) ? deg[i0 + 0] : 0;
  int d1 = (i0 + 1 < NN) ? deg[i0 + 1] : 0;
  int d2 = (i0 + 2 < NN) ? deg[i0 + 2] : 0;
  int d3 = (i0 + 3 < NN) ? deg[i0 + 3] : 0;
  int s4 = d0 + d1 + d2 + d3;
  sh[t] = s4;
  __syncthreads();
  int p = 0;
#pragma unroll
  for (int off = 1; off < 256; off <<= 1) {
    int v = (t >= off) ? sh[t - off] : 0;
    __syncthreads();
    sh[t] += v;
    __syncthreads();
  }
  p = sh[t] - s4;
  if (t == 255) bsum[b] = sh[255];
  if (i0 + 0 < NN) offs[i0 + 0] = p;
  if (i0 + 1 < NN) offs[i0 + 1] = p + d0;
  if (i0 + 2 < NN) offs[i0 + 2] = p + d0 + d1;
  if (i0 + 3 < NN) offs[i0 + 3] = p + d0 + d1 + d2;
}

__global__ void k_scan2(int* __restrict__ bsum, int* __restrict__ boff,
                        int* __restrict__ offs, int nb) {
  if (threadIdx.x == 0 && blockIdx.x == 0) {
    int run = 0;
    for (int k = 0; k < nb; ++k) { boff[k] = run; run += bsum[k]; }
    offs[NN] = NE;
  }
}

__global__ void k_scan3(int* __restrict__ offs, const int* __restrict__ boff,
                        int* __restrict__ cursor) {
  int i = blockIdx.x * 256 + threadIdx.x;
  if (i < NN) {
    int v = offs[i] + boff[i >> 10];
    offs[i] = v;
    cursor[i] = v;
  }
}

__global__ void k_scatter(const int* __restrict__ src, const int* __restrict__ dst,
                          int* __restrict__ cursor, int* __restrict__ csr_src,
                          int* __restrict__ posmap) {
  int e = blockIdx.x * 256 + threadIdx.x;
  if (e >= NE) return;
  int pos = atomicAdd(&cursor[dst[e]], 1);
  csr_src[pos] = src[e];
  posmap[e] = pos;
}

// ---------------- GAT conv path ----------------
__global__ void k_compute_v(const float* __restrict__ ew, const float* __restrict__ ae,
                            float* __restrict__ v) {
  int d = threadIdx.x >> 2, h = threadIdx.x & 3;
  float s = 0.f;
#pragma unroll
  for (int c = 0; c < NC; ++c) s = fmaf(ew[d * DD + h * NC + c], ae[h * NC + c], s);
  v[d * NH + h] = s;
}

// xh (bf16 out) + alpha_src/dst
__global__ void k_xh(const float* __restrict__ nf, const float* __restrict__ W,
                     const float* __restrict__ as_, const float* __restrict__ ad_,
                     __bf16* __restrict__ xh16, float* __restrict__ asrc,
                     float* __restrict__ adst) {
  int t = blockIdx.x * 4 + (threadIdx.x >> 6);
  int d = threadIdx.x & 63;
  if (t >= NN) return;
  const float* x = nf + (size_t)t * DD;
  float acc = 0.f;
#pragma unroll
  for (int k = 0; k < DD; ++k) acc = fmaf(x[k], W[k * DD + d], acc);
  xh16[(size_t)t * DD + d] = (__bf16)acc;
  int h = d >> 4, c = d & 15;
  float ps = acc * as_[h * NC + c];
  float pd = acc * ad_[h * NC + c];
#pragma unroll
  for (int off = 8; off >= 1; off >>= 1) {
    ps += __shfl_xor(ps, off, 64);
    pd += __shfl_xor(pd, off, 64);
  }
  if (c == 0) { asrc[t * NH + h] = ps; adst[t * NH + h] = pd; }
}

__global__ void k_pass1(const float* __restrict__ ef, const int* __restrict__ src,
                        const int* __restrict__ dst, const float* __restrict__ v,
                        const float* __restrict__ asrc, const float* __restrict__ adst,
                        const int* __restrict__ posmap, float* __restrict__ araw) {
  int e = blockIdx.x * 64 + (threadIdx.x >> 2);
  int part = threadIdx.x & 3;
  if (e >= NE) return;
  int s = src[e], t = dst[e];
  float ph0 = 0.f, ph1 = 0.f, ph2 = 0.f, ph3 = 0.f;
  const float4* ep = (const float4*)(ef + (size_t)e * DD + part * 16);
  const float4* v4 = (const float4*)v;
#pragma unroll
  for (int c4 = 0; c4 < 4; ++c4) {
    float4 x = ep[c4];
    int d0 = part * 16 + c4 * 4;
    float4 va = v4[d0], vb = v4[d0 + 1], vc = v4[d0 + 2], vd = v4[d0 + 3];
    ph0 = fmaf(x.x, va.x, fmaf(x.y, vb.x, fmaf(x.z, vc.x, fmaf(x.w, vd.x, ph0))));
    ph1 = fmaf(x.x, va.y, fmaf(x.y, vb.y, fmaf(x.z, vc.y, fmaf(x.w, vd.y, ph1))));
    ph2 = fmaf(x.x, va.z, fmaf(x.y, vb.z, fmaf(x.z, vc.z, fmaf(x.w, vd.z, ph2))));
    ph3 = fmaf(x.x, va.w, fmaf(x.y, vb.w, fmaf(x.z, vc.w, fmaf(x.w, vd.w, ph3))));
  }
#pragma unroll
  for (int off = 1; off <= 2; off <<= 1) {
    ph0 += __shfl_xor(ph0, off, 64);
    ph1 += __shfl_xor(ph1, off, 64);
    ph2 += __shfl_xor(ph2, off, 64);
    ph3 += __shfl_xor(ph3, off, 64);
  }
  float pe = (part == 0) ? ph0 : (part == 1) ? ph1 : (part == 2) ? ph2 : ph3;
  float a = asrc[s * NH + part] + adst[t * NH + part] + pe;
  a = (a > 0.f) ? a : SLOPE * a;
  araw[(size_t)posmap[e] * NH + part] = a;
}

// segment softmax + gather + conv_b + LN + relu + residual; emits nf fp32 + nf16
__global__ __launch_bounds__(256) void k_gather(
    const __bf16* __restrict__ xh16, const float* __restrict__ araw,
    const int* __restrict__ csr_src, const int* __restrict__ offs,
    const float* __restrict__ asrc, const float* __restrict__ adst,
    const float* __restrict__ cb, const float* __restrict__ g,
    const float* __restrict__ bln, float* __restrict__ nf,
    __bf16* __restrict__ nf16) {
  int t = blockIdx.x * 4 + (threadIdx.x >> 6);
  int d = threadIdx.x & 63;
  if (t >= NN) return;
  int h = d >> 4;
  int o0 = offs[t], o1 = offs[t + 1];
  int deg = o1 - o0;

  float m0 = -INFINITY, m1 = -INFINITY, m2 = -INFINITY, m3 = -INFINITY;
  for (int base = 0; base < deg; base += 64) {
    int j = base + d;
    if (j < deg) {
      float4 a = *(const float4*)(araw + (size_t)(o0 + j) * NH);
      m0 = fmaxf(m0, a.x); m1 = fmaxf(m1, a.y);
      m2 = fmaxf(m2, a.z); m3 = fmaxf(m3, a.w);
    }
  }
#pragma unroll
  for (int off = 32; off >= 1; off >>= 1) {
    m0 = fmaxf(m0, __shfl_xor(m0, off, 64));
    m1 = fmaxf(m1, __shfl_xor(m1, off, 64));
    m2 = fmaxf(m2, __shfl_xor(m2, off, 64));
    m3 = fmaxf(m3, __shfl_xor(m3, off, 64));
  }
  float sh = asrc[t * NH + h] + adst[t * NH + h];
  sh = (sh > 0.f) ? sh : SLOPE * sh;
  float mh = (h == 0) ? m0 : (h == 1) ? m1 : (h == 2) ? m2 : m3;
  mh = fmaxf(mh, sh);

  float acc = 0.f, wsum = 0.f;
  int j = 0;
  for (; j + 1 < deg; j += 2) {
    int sp0 = csr_src[o0 + j], sp1 = csr_src[o0 + j + 1];
    float ar0 = araw[(size_t)(o0 + j) * NH + h];
    float ar1 = araw[(size_t)(o0 + j + 1) * NH + h];
    float w0 = expf(ar0 - mh), w1 = expf(ar1 - mh);
    acc = fmaf(w0, (float)xh16[(size_t)sp0 * DD + d], acc);
    acc = fmaf(w1, (float)xh16[(size_t)sp1 * DD + d], acc);
    wsum += w0 + w1;
  }
  if (j < deg) {
    int sp = csr_src[o0 + j];
    float ar = araw[(size_t)(o0 + j) * NH + h];
    float w = expf(ar - mh);
    acc = fmaf(w, (float)xh16[(size_t)sp * DD + d], acc);
    wsum += w;
  }
  float wself = expf(sh - mh);
  acc = fmaf(wself, (float)xh16[(size_t)t * DD + d], acc);
  wsum += wself;

  float val = acc / (wsum + 1e-16f) + cb[d];
  float m = val;
#pragma unroll
  for (int off = 32; off >= 1; off >>= 1) m += __shfl_xor(m, off, 64);
  m *= (1.f / 64.f);
  float c = val - m;
  float q = c * c;
#pragma unroll
  for (int off = 32; off >= 1; off >>= 1) q += __shfl_xor(q, off, 64);
  float rstd = 1.f / sqrtf(q * (1.f / 64.f) + 1e-5f);
  float y = c * rstd * g[d] + bln[d];
  y = fmaxf(y, 0.f);
  float out = y + nf[(size_t)t * DD + d];
  nf[(size_t)t * DD + d] = out;
  nf16[(size_t)t * DD + d] = (__bf16)out;
}

// ---------------- edge MLP v5: single-bf16 W, bf16 staging, 3 blocks/CU -------
// 128 edges/block, 8 waves (2 rg x 4 cg). Wave: rows rg*64+rt*16 (rt 0..3),
// GEMM1 cols cg*48+t*16 (t 0..2), GEMM2 cols cg*16.
__global__ __launch_bounds__(512, 8) void k_edge_mlp5(
    const __bf16* __restrict__ nf16, float* __restrict__ ef,
    const int* __restrict__ src, const int* __restrict__ dst,
    const __bf16* __restrict__ W1H, const float* __restrict__ b1,
    const float* __restrict__ g, const float* __restrict__ bg,
    const __bf16* __restrict__ W2H, const float* __restrict__ b2) {
  __shared__ __bf16 XH[EB * XSTR];   // 51200 B: X during GEMM1, H after
  __shared__ __bf16 Pb[EB * 8];      // 2048 B: LN partials (sm,sq) x 4cg, bf16
  int tid = threadIdx.x;
  int e0 = blockIdx.x * EB;

  // stage X: thread owns (row = tid>>2, part p = tid&3); nf16 copied raw,
  // ef converted fp32->bf16
  {
    int row = tid >> 2, p = tid & 3;
    int se = src[e0 + row], de = dst[e0 + row];
    const bf8* psrc = (const bf8*)(nf16 + (size_t)se * DD + p * 16);
    *(bf8*)&XH[row * XSTR + p * 16]     = psrc[0];
    *(bf8*)&XH[row * XSTR + p * 16 + 8] = psrc[1];
    const bf8* pdst = (const bf8*)(nf16 + (size_t)de * DD + p * 16);
    *(bf8*)&XH[row * XSTR + 64 + p * 16]     = pdst[0];
    *(bf8*)&XH[row * XSTR + 64 + p * 16 + 8] = pdst[1];
    const float4* pef = (const float4*)(ef + (size_t)(e0 + row) * DD + p * 16);
#pragma unroll
    for (int k = 0; k < 4; ++k) {
      float4 v = pef[k];
      bf4 hv;
      hv[0] = (__bf16)v.x; hv[1] = (__bf16)v.y;
      hv[2] = (__bf16)v.z; hv[3] = (__bf16)v.w;
      *(bf4*)&XH[row * XSTR + 128 + p * 16 + k * 4] = hv;
    }
  }
  __syncthreads();

  int w = tid >> 6, l = tid & 63;
  int rg = w >> 2, cg = w & 3;
  int gq = l >> 4, i = l & 15;

  f32x4 acc[4][3];
#pragma unroll
  for (int rt = 0; rt < 4; ++rt)
#pragma unroll
    for (int t = 0; t < 3; ++t) acc[rt][t] = (f32x4){0.f, 0.f, 0.f, 0.f};

  // GEMM1: no barriers; B-tiles from global (L2-hot)
#pragma unroll
  for (int s = 0; s < 6; ++s) {
    bf8 a[4];
#pragma unroll
    for (int rt = 0; rt < 4; ++rt)
      a[rt] = *(const bf8*)&XH[(rg * 64 + rt * 16 + i) * XSTR + s * 32 + gq * 8];
#pragma unroll
    for (int t = 0; t < 3; ++t) {
      bf8 bh = *(const bf8*)(W1H + ((size_t)((cg * 3 + t) * 6 + s) * 64 + l) * 8);
#pragma unroll
      for (int rt = 0; rt < 4; ++rt) acc[rt][t] = MFMA(a[rt], bh, acc[rt][t]);
    }
  }

  float b1v[3], gv[3], bgv[3];
#pragma unroll
  for (int t = 0; t < 3; ++t) {
    int n = cg * 48 + t * 16 + i;
    b1v[t] = b1[n]; gv[t] = g[n]; bgv[t] = bg[n];
  }
#pragma unroll
  for (int rt = 0; rt < 4; ++rt)
#pragma unroll
    for (int t = 0; t < 3; ++t)
#pragma unroll
      for (int r = 0; r < 4; ++r) acc[rt][t][r] += b1v[t];

#pragma unroll
  for (int rt = 0; rt < 4; ++rt)
#pragma unroll
    for (int r = 0; r < 4; ++r) {
      float sm = 0.f, sq = 0.f;
#pragma unroll
      for (int t = 0; t < 3; ++t) { float x = acc[rt][t][r]; sm += x; sq = fmaf(x, x, sq); }
#pragma unroll
      for (int off = 1; off <= 8; off <<= 1) {
        sm += __shfl_xor(sm, off, 64);
        sq += __shfl_xor(sq, off, 64);
      }
      if (i == 0) {
        int row = rg * 64 + rt * 16 + gq * 4 + r;
        bf2 pr; pr[0] = (__bf16)sm; pr[1] = (__bf16)sq;
        *(bf2*)&Pb[row * 8 + cg * 2] = pr;
      }
    }
  __syncthreads();   // barrier 1: Pb ready AND all GEMM1 X-reads done

  // finalize LN, relu, write H over X
#pragma unroll
  for (int rt = 0; rt < 4; ++rt)
#pragma unroll
    for (int r = 0; r < 4; ++r) {
      int row = rg * 64 + rt * 16 + gq * 4 + r;
      bf8 pv = *(const bf8*)&Pb[row * 8];
      float sm = (float)pv[0] + (float)pv[2] + (float)pv[4] + (float)pv[6];
      float sq = (float)pv[1] + (float)pv[3] + (float)pv[5] + (float)pv[7];
      float mean = sm * (1.f / (float)DIN);
      float var = sq * (1.f / (float)DIN) - mean * mean;
      float rstd = 1.f / sqrtf(var + 1e-5f);
#pragma unroll
      for (int t = 0; t < 3; ++t) {
        float y = (acc[rt][t][r] - mean) * rstd * gv[t] + bgv[t];
        y = fmaxf(y, 0.f);
        XH[row * XSTR + cg * 48 + t * 16 + i] = (__bf16)y;
      }
    }
  __syncthreads();   // barrier 2: H fully published

  // GEMM2
  f32x4 acc2[4];
#pragma unroll
  for (int rt = 0; rt < 4; ++rt) acc2[rt] = (f32x4){0.f, 0.f, 0.f, 0.f};

#pragma unroll
  for (int s = 0; s < 6; ++s) {
    bf8 a2[4];
#pragma unroll
    for (int rt = 0; rt < 4; ++rt)
      a2[rt] = *(const bf8*)&XH[(rg * 64 + rt * 16 + i) * XSTR + s * 32 + gq * 8];
    bf8 bh = *(const bf8*)(W2H + ((size_t)(cg * 6 + s) * 64 + l) * 8);
#pragma unroll
    for (int rt = 0; rt < 4; ++rt) acc2[rt] = MFMA(a2[rt], bh, acc2[rt]);
  }

  float b2v = b2[cg * 16 + i];
  int col = cg * 16 + i;
#pragma unroll
  for (int rt = 0; rt < 4; ++rt)
#pragma unroll
    for (int r = 0; r < 4; ++r) {
      int row = rg * 64 + rt * 16 + gq * 4 + r;
      float res = ef[(size_t)(e0 + row) * DD + col];   // original ef, fp32
      ef[(size_t)(e0 + row) * DD + col] = acc2[rt][r] + b2v + res;
    }
}

extern "C" void kernel_launch(void* const* d_in, const int* in_sizes, int n_in,
                              void* d_out, int out_size, void* d_ws, size_t ws_size,
                              hipStream_t stream) {
  const float* node_feats = (const float*)d_in[0];
  const float* edge_feats = (const float*)d_in[1];
  const int*   edge_index = (const int*)d_in[2];
  const float* conv_w  = (const float*)d_in[3];
  const float* att_src = (const float*)d_in[4];
  const float* att_dst = (const float*)d_in[5];
  const float* edge_w  = (const float*)d_in[6];
  const float* att_edge= (const float*)d_in[7];
  const float* conv_b  = (const float*)d_in[8];
  const float* ln_g    = (const float*)d_in[9];
  const float* ln_b    = (const float*)d_in[10];
  const float* up1_w   = (const float*)d_in[11];
  const float* up1_b   = (const float*)d_in[12];
  const float* up_ln_g = (const float*)d_in[13];
  const float* up_ln_b = (const float*)d_in[14];
  const float* up2_w   = (const float*)d_in[15];
  const float* up2_b   = (const float*)d_in[16];

  const int* src = edge_index;
  const int* dst = edge_index + NE;

  float* nf = (float*)d_out;
  float* ef = nf + (size_t)NN * DD;

  float* w = (float*)d_ws;
  __bf16* xh16 = (__bf16*)w; w += (size_t)NN * DD / 2;
  __bf16* nf16 = (__bf16*)w; w += (size_t)NN * DD / 2;
  float* asrc  = w; w += (size_t)NN * NH;
  float* adst  = w; w += (size_t)NN * NH;
  float* araw  = w; w += (size_t)NE * NH;
  float* vbuf  = w; w += 256;
  __bf16* W1H = (__bf16*)w; w += (size_t)4 * 36864 / 2;
  __bf16* W2H = (__bf16*)w; w += (size_t)4 * 12288 / 2;
  int* deg     = (int*)w; w += NN;
  int* offs    = (int*)w; w += NN + 1;
  int* cursor  = (int*)w; w += NN;
  int* bsum    = (int*)w; w += 128;
  int* boff    = (int*)w; w += 128;
  int* csr_src = (int*)w; w += NE;
  int* posmap  = (int*)w; w += NE;

  hipMemcpyAsync(nf, node_feats, (size_t)NN * DD * sizeof(float),
                 hipMemcpyDeviceToDevice, stream);
  hipMemcpyAsync(ef, edge_feats, (size_t)NE * DD * sizeof(float),
                 hipMemcpyDeviceToDevice, stream);

  k_pack_w1<<<72, 256, 0, stream>>>(up1_w, W1H);
  k_pack_w2<<<24, 256, 0, stream>>>(up2_w, W2H);

  const int nb = (NN + 1023) / 1024;
  k_zero<<<(NN + 255) / 256, 256, 0, stream>>>(deg);
  k_hist<<<(NE + 255) / 256, 256, 0, stream>>>(dst, deg);
  k_scan1<<<nb, 256, 0, stream>>>(deg, offs, bsum);
  k_scan2<<<1, 64, 0, stream>>>(bsum, boff, offs, nb);
  k_scan3<<<(NN + 255) / 256, 256, 0, stream>>>(offs, boff, cursor);
  k_scatter<<<(NE + 255) / 256, 256, 0, stream>>>(src, dst, cursor, csr_src, posmap);

  for (int l = 0; l < NL; ++l) {
    k_compute_v<<<1, 256, 0, stream>>>(edge_w + (size_t)l * DD * DD,
                                       att_edge + (size_t)l * NH * NC, vbuf);
    k_xh<<<NN / 4, 256, 0, stream>>>(nf, conv_w + (size_t)l * DD * DD,
                                     att_src + (size_t)l * NH * NC,
                                     att_dst + (size_t)l * NH * NC, xh16, asrc, adst);
    k_pass1<<<NE / 64, 256, 0, stream>>>(ef, src, dst, vbuf, asrc, adst, posmap, araw);
    k_gather<<<NN / 4, 256, 0, stream>>>(xh16, araw, csr_src, offs, asrc, adst,
                                         conv_b + (size_t)l * DD,
                                         ln_g + (size_t)l * DD,
                                         ln_b + (size_t)l * DD, nf, nf16);
    k_edge_mlp5<<<NE / EB, 512, 0, stream>>>(
        nf16, ef, src, dst,
        W1H + (size_t)l * 36864, up1_b + (size_t)l * DIN,
        up_ln_g + (size_t)l * DIN, up_ln_b + (size_t)l * DIN,
        W2H + (size_t)l * 12288, up2_b + (size_t)l * DD);
  }
}

// Round 9
// 3804.917 us; speedup vs baseline: 3.5041x; 1.0059x over previous
//
#include <hip/hip_runtime.h>
#include <math.h>

#define NN 100000
#define NE 1600000
#define DD 64
#define NL 4
#define NH 4
#define NC 16
#define DIN 192
#define SLOPE 0.2f
#define EB 128
#define XSTR 200
#define LOG2E 1.44269504088896340736f

typedef __bf16 bf8 __attribute__((ext_vector_type(8)));
typedef __bf16 bf4 __attribute__((ext_vector_type(4)));
typedef __bf16 bf2 __attribute__((ext_vector_type(2)));
typedef float f32x4 __attribute__((ext_vector_type(4)));

__device__ __forceinline__ f32x4 MFMA(bf8 a, bf8 b, f32x4 c) {
  return __builtin_amdgcn_mfma_f32_16x16x32_bf16(a, b, c, 0, 0, 0);
}

// ---------------- weight packing: single bf16 plane, 1KB tiles ----------------
// tile (t,s): lane l holds W[k][n], k=s*32+(l>>4)*8+j, n=t*16+(l&15), j=0..7
__global__ void k_pack_w1(const float* __restrict__ W1, __bf16* __restrict__ WH) {
  int gidx = blockIdx.x * 256 + threadIdx.x;
  if (gidx >= 4 * 4608) return;
  int lyr = gidx / 4608, rem = gidx % 4608;
  int lane = rem & 63, ts = rem >> 6;
  int s = ts % 6, t = ts / 6;
  const float* Wl = W1 + (size_t)lyr * DIN * DIN;
  size_t base = (size_t)lyr * 36864 + ((size_t)(t * 6 + s) * 64 + lane) * 8;
  int k0 = s * 32 + (lane >> 4) * 8, n = t * 16 + (lane & 15);
#pragma unroll
  for (int j = 0; j < 8; ++j)
    WH[base + j] = (__bf16)Wl[(size_t)(k0 + j) * DIN + n];
}

__global__ void k_pack_w2(const float* __restrict__ W2, __bf16* __restrict__ WH) {
  int gidx = blockIdx.x * 256 + threadIdx.x;
  if (gidx >= 4 * 1536) return;
  int lyr = gidx / 1536, rem = gidx % 1536;
  int lane = rem & 63, ts = rem >> 6;
  int s = ts % 6, t = ts / 6;
  const float* Wl = W2 + (size_t)lyr * DIN * DD;
  size_t base = (size_t)lyr * 12288 + ((size_t)(t * 6 + s) * 64 + lane) * 8;
  int k0 = s * 32 + (lane >> 4) * 8, n = t * 16 + (lane & 15);
#pragma unroll
  for (int j = 0; j < 8; ++j)
    WH[base + j] = (__bf16)Wl[(size_t)(k0 + j) * DD + n];
}

// ---------------- CSR build (once per launch; graph is static) ----------------
__global__ void k_zero(int* __restrict__ deg) {
  int i = blockIdx.x * 256 + threadIdx.x;
  if (i < NN) deg[i] = 0;
}

__global__ void k_hist(const int* __restrict__ dst, int* __restrict__ deg) {
  int e = blockIdx.x * 256 + threadIdx.x;
  if (e < NE) atomicAdd(&deg[dst[e]], 1);
}

__global__ void k_scan1(const int* __restrict__ deg, int* __restrict__ offs,
                        int* __restrict__ bsum) {
  __shared__ int sh[256];
  int t = threadIdx.x, b = blockIdx.x;
  int i0 = b * 1024 + t * 4;
  int d0 = (i0 + 0 < NN) ? deg[i0 + 0] : 0;
  int d1 = (i0 + 1 < NN) ? deg[i0 + 1] : 0;
  int d2 = (i0 + 2 < NN) ? deg[i0 + 2] : 0;
  int d3 = (i0 + 3 < NN) ? deg[i0 + 3] : 0;
  int s4 = d0 + d1 + d2 + d3;
  sh[t] = s4;
  __syncthreads();
  int p = 0;
#pragma unroll
  for (int off = 1; off < 256; off <<= 1) {
    int v = (t >= off) ? sh[t - off] : 0;
    __syncthreads();
    sh[t] += v;
    __syncthreads();
  }
  p = sh[t] - s4;
  if (t == 255) bsum[b] = sh[255];
  if (i0 + 0 < NN) offs[i0 + 0] = p;
  if (i0 + 1 < NN) offs[i0 + 1] = p + d0;
  if (i0 + 2 < NN) offs[i0 + 2] = p + d0 + d1;
  if (i0 + 3 < NN) offs[i0 + 3] = p + d0 + d1 + d2;
}

__global__ void k_scan2(int* __restrict__ bsum, int* __restrict__ boff,
                        int* __restrict__ offs, int nb) {
  if (threadIdx.x == 0 && blockIdx.x == 0) {
    int run = 0;
    for (int k = 0; k < nb; ++k) { boff[k] = run; run += bsum[k]; }
    offs[NN] = NE;
  }
}

__global__ void k_scan3(int* __restrict__ offs, const int* __restrict__ boff,
                        int* __restrict__ cursor) {
  int i = blockIdx.x * 256 + threadIdx.x;
  if (i < NN) {
    int v = offs[i] + boff[i >> 10];
    offs[i] = v;
    cursor[i] = v;
  }
}

__global__ void k_scatter(const int* __restrict__ src, const int* __restrict__ dst,
                          int* __restrict__ cursor, int* __restrict__ csr_src,
                          int* __restrict__ posmap) {
  int e = blockIdx.x * 256 + threadIdx.x;
  if (e >= NE) return;
  int pos = atomicAdd(&cursor[dst[e]], 1);
  csr_src[pos] = src[e];
  posmap[e] = pos;
}

// ---------------- GAT conv path ----------------
__global__ void k_compute_v(const float* __restrict__ ew, const float* __restrict__ ae,
                            float* __restrict__ v) {
  int d = threadIdx.x >> 2, h = threadIdx.x & 3;
  float s = 0.f;
#pragma unroll
  for (int c = 0; c < NC; ++c) s = fmaf(ew[d * DD + h * NC + c], ae[h * NC + c], s);
  v[d * NH + h] = s;
}

// xh (bf16 out) + alpha_src/dst
__global__ void k_xh(const float* __restrict__ nf, const float* __restrict__ W,
                     const float* __restrict__ as_, const float* __restrict__ ad_,
                     __bf16* __restrict__ xh16, float* __restrict__ asrc,
                     float* __restrict__ adst) {
  int t = blockIdx.x * 4 + (threadIdx.x >> 6);
  int d = threadIdx.x & 63;
  if (t >= NN) return;
  const float* x = nf + (size_t)t * DD;
  float acc = 0.f;
#pragma unroll
  for (int k = 0; k < DD; ++k) acc = fmaf(x[k], W[k * DD + d], acc);
  xh16[(size_t)t * DD + d] = (__bf16)acc;
  int h = d >> 4, c = d & 15;
  float ps = acc * as_[h * NC + c];
  float pd = acc * ad_[h * NC + c];
#pragma unroll
  for (int off = 8; off >= 1; off >>= 1) {
    ps += __shfl_xor(ps, off, 64);
    pd += __shfl_xor(pd, off, 64);
  }
  if (c == 0) { asrc[t * NH + h] = ps; adst[t * NH + h] = pd; }
}

// pass1: alpha logits pre-scaled by log2(e) (consumer uses exp2)
__global__ void k_pass1(const float* __restrict__ ef, const int* __restrict__ src,
                        const int* __restrict__ dst, const float* __restrict__ v,
                        const float* __restrict__ asrc, const float* __restrict__ adst,
                        const int* __restrict__ posmap, float* __restrict__ araw) {
  int e = blockIdx.x * 64 + (threadIdx.x >> 2);
  int part = threadIdx.x & 3;
  if (e >= NE) return;
  int s = src[e], t = dst[e];
  float ph0 = 0.f, ph1 = 0.f, ph2 = 0.f, ph3 = 0.f;
  const float4* ep = (const float4*)(ef + (size_t)e * DD + part * 16);
  const float4* v4 = (const float4*)v;
#pragma unroll
  for (int c4 = 0; c4 < 4; ++c4) {
    float4 x = ep[c4];
    int d0 = part * 16 + c4 * 4;
    float4 va = v4[d0], vb = v4[d0 + 1], vc = v4[d0 + 2], vd = v4[d0 + 3];
    ph0 = fmaf(x.x, va.x, fmaf(x.y, vb.x, fmaf(x.z, vc.x, fmaf(x.w, vd.x, ph0))));
    ph1 = fmaf(x.x, va.y, fmaf(x.y, vb.y, fmaf(x.z, vc.y, fmaf(x.w, vd.y, ph1))));
    ph2 = fmaf(x.x, va.z, fmaf(x.y, vb.z, fmaf(x.z, vc.z, fmaf(x.w, vd.z, ph2))));
    ph3 = fmaf(x.x, va.w, fmaf(x.y, vb.w, fmaf(x.z, vc.w, fmaf(x.w, vd.w, ph3))));
  }
#pragma unroll
  for (int off = 1; off <= 2; off <<= 1) {
    ph0 += __shfl_xor(ph0, off, 64);
    ph1 += __shfl_xor(ph1, off, 64);
    ph2 += __shfl_xor(ph2, off, 64);
    ph3 += __shfl_xor(ph3, off, 64);
  }
  float pe = (part == 0) ? ph0 : (part == 1) ? ph1 : (part == 2) ? ph2 : ph3;
  float a = asrc[s * NH + part] + adst[t * NH + part] + pe;
  a = (a > 0.f) ? a : SLOPE * a;
  araw[(size_t)posmap[e] * NH + part] = a * LOG2E;
}

// segment softmax (exp2 domain) + gather + conv_b + LN + relu + residual
__global__ __launch_bounds__(256) void k_gather(
    const __bf16* __restrict__ xh16, const float* __restrict__ araw,
    const int* __restrict__ csr_src, const int* __restrict__ offs,
    const float* __restrict__ asrc, const float* __restrict__ adst,
    const float* __restrict__ cb, const float* __restrict__ g,
    const float* __restrict__ bln, float* __restrict__ nf,
    __bf16* __restrict__ nf16) {
  int t = blockIdx.x * 4 + (threadIdx.x >> 6);
  int d = threadIdx.x & 63;
  if (t >= NN) return;
  int h = d >> 4;
  int o0 = offs[t], o1 = offs[t + 1];
  int deg = o1 - o0;

  float m0 = -INFINITY, m1 = -INFINITY, m2 = -INFINITY, m3 = -INFINITY;
  for (int base = 0; base < deg; base += 64) {
    int j = base + d;
    if (j < deg) {
      float4 a = *(const float4*)(araw + (size_t)(o0 + j) * NH);
      m0 = fmaxf(m0, a.x); m1 = fmaxf(m1, a.y);
      m2 = fmaxf(m2, a.z); m3 = fmaxf(m3, a.w);
    }
  }
#pragma unroll
  for (int off = 32; off >= 1; off >>= 1) {
    m0 = fmaxf(m0, __shfl_xor(m0, off, 64));
    m1 = fmaxf(m1, __shfl_xor(m1, off, 64));
    m2 = fmaxf(m2, __shfl_xor(m2, off, 64));
    m3 = fmaxf(m3, __shfl_xor(m3, off, 64));
  }
  float sh = asrc[t * NH + h] + adst[t * NH + h];
  sh = ((sh > 0.f) ? sh : SLOPE * sh) * LOG2E;
  float mh = (h == 0) ? m0 : (h == 1) ? m1 : (h == 2) ? m2 : m3;
  mh = fmaxf(mh, sh);

  float acc = 0.f, wsum = 0.f;
  int j = 0;
  for (; j + 1 < deg; j += 2) {
    int sp0 = csr_src[o0 + j], sp1 = csr_src[o0 + j + 1];
    float ar0 = araw[(size_t)(o0 + j) * NH + h];
    float ar1 = araw[(size_t)(o0 + j + 1) * NH + h];
    float w0 = exp2f(ar0 - mh), w1 = exp2f(ar1 - mh);
    acc = fmaf(w0, (float)xh16[(size_t)sp0 * DD + d], acc);
    acc = fmaf(w1, (float)xh16[(size_t)sp1 * DD + d], acc);
    wsum += w0 + w1;
  }
  if (j < deg) {
    int sp = csr_src[o0 + j];
    float ar = araw[(size_t)(o0 + j) * NH + h];
    float w = exp2f(ar - mh);
    acc = fmaf(w, (float)xh16[(size_t)sp * DD + d], acc);
    wsum += w;
  }
  float wself = exp2f(sh - mh);
  acc = fmaf(wself, (float)xh16[(size_t)t * DD + d], acc);
  wsum += wself;

  float val = acc / (wsum + 1e-16f) + cb[d];
  float m = val;
#pragma unroll
  for (int off = 32; off >= 1; off >>= 1) m += __shfl_xor(m, off, 64);
  m *= (1.f / 64.f);
  float c = val - m;
  float q = c * c;
#pragma unroll
  for (int off = 32; off >= 1; off >>= 1) q += __shfl_xor(q, off, 64);
  float rstd = 1.f / sqrtf(q * (1.f / 64.f) + 1e-5f);
  float y = c * rstd * g[d] + bln[d];
  y = fmaxf(y, 0.f);
  float out = y + nf[(size_t)t * DD + d];
  nf[(size_t)t * DD + d] = out;
  nf16[(size_t)t * DD + d] = (__bf16)out;
}

// ---------------- edge MLP v6: de-duplicated LN finalize ----------------------
// 128 edges/block, 8 waves (2 rg x 4 cg). Wave: rows rg*64+rt*16 (rt 0..3),
// GEMM1 cols cg*48+t*16 (t 0..2), GEMM2 cols cg*16.
__global__ __launch_bounds__(512, 8) void k_edge_mlp6(
    const __bf16* __restrict__ nf16, float* __restrict__ ef,
    const int* __restrict__ src, const int* __restrict__ dst,
    const __bf16* __restrict__ W1H, const float* __restrict__ b1,
    const float* __restrict__ g, const float* __restrict__ bg,
    const __bf16* __restrict__ W2H, const float* __restrict__ b2) {
  __shared__ __bf16 XH[EB * XSTR];   // 51200 B: X during GEMM1, H after
  __shared__ __bf16 Pb[EB * 8];      // 2048 B: LN partials; slot 0 reused (mean,rstd)
  int tid = threadIdx.x;
  int e0 = blockIdx.x * EB;

  // stage X: thread owns (row = tid>>2, part p = tid&3)
  {
    int row = tid >> 2, p = tid & 3;
    int se = src[e0 + row], de = dst[e0 + row];
    const bf8* psrc = (const bf8*)(nf16 + (size_t)se * DD + p * 16);
    *(bf8*)&XH[row * XSTR + p * 16]     = psrc[0];
    *(bf8*)&XH[row * XSTR + p * 16 + 8] = psrc[1];
    const bf8* pdst = (const bf8*)(nf16 + (size_t)de * DD + p * 16);
    *(bf8*)&XH[row * XSTR + 64 + p * 16]     = pdst[0];
    *(bf8*)&XH[row * XSTR + 64 + p * 16 + 8] = pdst[1];
    const float4* pef = (const float4*)(ef + (size_t)(e0 + row) * DD + p * 16);
#pragma unroll
    for (int k = 0; k < 4; ++k) {
      float4 v = pef[k];
      bf4 hv;
      hv[0] = (__bf16)v.x; hv[1] = (__bf16)v.y;
      hv[2] = (__bf16)v.z; hv[3] = (__bf16)v.w;
      *(bf4*)&XH[row * XSTR + 128 + p * 16 + k * 4] = hv;
    }
  }
  __syncthreads();

  int w = tid >> 6, l = tid & 63;
  int rg = w >> 2, cg = w & 3;
  int gq = l >> 4, i = l & 15;

  f32x4 acc[4][3];
#pragma unroll
  for (int rt = 0; rt < 4; ++rt)
#pragma unroll
    for (int t = 0; t < 3; ++t) acc[rt][t] = (f32x4){0.f, 0.f, 0.f, 0.f};

  // GEMM1: no barriers; B-tiles from global (L2-hot)
#pragma unroll
  for (int s = 0; s < 6; ++s) {
    bf8 a[4];
#pragma unroll
    for (int rt = 0; rt < 4; ++rt)
      a[rt] = *(const bf8*)&XH[(rg * 64 + rt * 16 + i) * XSTR + s * 32 + gq * 8];
#pragma unroll
    for (int t = 0; t < 3; ++t) {
      bf8 bh = *(const bf8*)(W1H + ((size_t)((cg * 3 + t) * 6 + s) * 64 + l) * 8);
#pragma unroll
      for (int rt = 0; rt < 4; ++rt) acc[rt][t] = MFMA(a[rt], bh, acc[rt][t]);
    }
  }

  float b1v[3], gv[3], bgv[3];
#pragma unroll
  for (int t = 0; t < 3; ++t) {
    int n = cg * 48 + t * 16 + i;
    b1v[t] = b1[n]; gv[t] = g[n]; bgv[t] = bg[n];
  }
#pragma unroll
  for (int rt = 0; rt < 4; ++rt)
#pragma unroll
    for (int t = 0; t < 3; ++t)
#pragma unroll
      for (int r = 0; r < 4; ++r) acc[rt][t][r] += b1v[t];

#pragma unroll
  for (int rt = 0; rt < 4; ++rt)
#pragma unroll
    for (int r = 0; r < 4; ++r) {
      float sm = 0.f, sq = 0.f;
#pragma unroll
      for (int t = 0; t < 3; ++t) { float x = acc[rt][t][r]; sm += x; sq = fmaf(x, x, sq); }
#pragma unroll
      for (int off = 1; off <= 8; off <<= 1) {
        sm += __shfl_xor(sm, off, 64);
        sq += __shfl_xor(sq, off, 64);
      }
      if (i == 0) {
        int row = rg * 64 + rt * 16 + gq * 4 + r;
        bf2 pr; pr[0] = (__bf16)sm; pr[1] = (__bf16)sq;
        *(bf2*)&Pb[row * 8 + cg * 2] = pr;
      }
    }
  __syncthreads();   // barrier 1: Pb partials ready AND all GEMM1 X-reads done

  // per-row finalize, once (thread tid<128 owns row tid); result into slot 0
  if (tid < EB) {
    bf8 pv = *(const bf8*)&Pb[tid * 8];
    float sm = (float)pv[0] + (float)pv[2] + (float)pv[4] + (float)pv[6];
    float sq = (float)pv[1] + (float)pv[3] + (float)pv[5] + (float)pv[7];
    float mean = sm * (1.f / (float)DIN);
    float var = sq * (1.f / (float)DIN) - mean * mean;
    float rstd = 1.f / sqrtf(var + 1e-5f);
    bf2 mv; mv[0] = (__bf16)mean; mv[1] = (__bf16)rstd;
    *(bf2*)&Pb[tid * 8] = mv;
  }
  __syncthreads();   // barrier 2: (mean,rstd) ready

  // LN apply + relu, write H over X
#pragma unroll
  for (int rt = 0; rt < 4; ++rt)
#pragma unroll
    for (int r = 0; r < 4; ++r) {
      int row = rg * 64 + rt * 16 + gq * 4 + r;
      bf2 mv = *(const bf2*)&Pb[row * 8];
      float mean = (float)mv[0], rstd = (float)mv[1];
#pragma unroll
      for (int t = 0; t < 3; ++t) {
        float y = (acc[rt][t][r] - mean) * rstd * gv[t] + bgv[t];
        y = fmaxf(y, 0.f);
        XH[row * XSTR + cg * 48 + t * 16 + i] = (__bf16)y;
      }
    }
  __syncthreads();   // barrier 3: H fully published

  // GEMM2
  f32x4 acc2[4];
#pragma unroll
  for (int rt = 0; rt < 4; ++rt) acc2[rt] = (f32x4){0.f, 0.f, 0.f, 0.f};

#pragma unroll
  for (int s = 0; s < 6; ++s) {
    bf8 a2[4];
#pragma unroll
    for (int rt = 0; rt < 4; ++rt)
      a2[rt] = *(const bf8*)&XH[(rg * 64 + rt * 16 + i) * XSTR + s * 32 + gq * 8];
    bf8 bh = *(const bf8*)(W2H + ((size_t)(cg * 6 + s) * 64 + l) * 8);
#pragma unroll
    for (int rt = 0; rt < 4; ++rt) acc2[rt] = MFMA(a2[rt], bh, acc2[rt]);
  }

  float b2v = b2[cg * 16 + i];
  int col = cg * 16 + i;
#pragma unroll
  for (int rt = 0; rt < 4; ++rt)
#pragma unroll
    for (int r = 0; r < 4; ++r) {
      int row = rg * 64 + rt * 16 + gq * 4 + r;
      float res = ef[(size_t)(e0 + row) * DD + col];   // original ef, fp32
      ef[(size_t)(e0 + row) * DD + col] = acc2[rt][r] + b2v + res;
    }
}

extern "C" void kernel_launch(void* const* d_in, const int* in_sizes, int n_in,
                              void* d_out, int out_size, void* d_ws, size_t ws_size,
                              hipStream_t stream) {
  const float* node_feats = (const float*)d_in[0];
  const float* edge_feats = (const float*)d_in[1];
  const int*   edge_index = (const int*)d_in[2];
  const float* conv_w  = (const float*)d_in[3];
  const float* att_src = (const float*)d_in[4];
  const float* att_dst = (const float*)d_in[5];
  const float* edge_w  = (const float*)d_in[6];
  const float* att_edge= (const float*)d_in[7];
  const float* conv_b  = (const float*)d_in[8];
  const float* ln_g    = (const float*)d_in[9];
  const float* ln_b    = (const float*)d_in[10];
  const float* up1_w   = (const float*)d_in[11];
  const float* up1_b   = (const float*)d_in[12];
  const float* up_ln_g = (const float*)d_in[13];
  const float* up_ln_b = (const float*)d_in[14];
  const float* up2_w   = (const float*)d_in[15];
  const float* up2_b   = (const float*)d_in[16];

  const int* src = edge_index;
  const int* dst = edge_index + NE;

  float* nf = (float*)d_out;
  float* ef = nf + (size_t)NN * DD;

  float* w = (float*)d_ws;
  __bf16* xh16 = (__bf16*)w; w += (size_t)NN * DD / 2;
  __bf16* nf16 = (__bf16*)w; w += (size_t)NN * DD / 2;
  float* asrc  = w; w += (size_t)NN * NH;
  float* adst  = w; w += (size_t)NN * NH;
  float* araw  = w; w += (size_t)NE * NH;
  float* vbuf  = w; w += 256;
  __bf16* W1H = (__bf16*)w; w += (size_t)4 * 36864 / 2;
  __bf16* W2H = (__bf16*)w; w += (size_t)4 * 12288 / 2;
  int* deg     = (int*)w; w += NN;
  int* offs    = (int*)w; w += NN + 1;
  int* cursor  = (int*)w; w += NN;
  int* bsum    = (int*)w; w += 128;
  int* boff    = (int*)w; w += 128;
  int* csr_src = (int*)w; w += NE;
  int* posmap  = (int*)w; w += NE;

  hipMemcpyAsync(nf, node_feats, (size_t)NN * DD * sizeof(float),
                 hipMemcpyDeviceToDevice, stream);
  hipMemcpyAsync(ef, edge_feats, (size_t)NE * DD * sizeof(float),
                 hipMemcpyDeviceToDevice, stream);

  k_pack_w1<<<72, 256, 0, stream>>>(up1_w, W1H);
  k_pack_w2<<<24, 256, 0, stream>>>(up2_w, W2H);

  const int nb = (NN + 1023) / 1024;
  k_zero<<<(NN + 255) / 256, 256, 0, stream>>>(deg);
  k_hist<<<(NE + 255) / 256, 256, 0, stream>>>(dst, deg);
  k_scan1<<<nb, 256, 0, stream>>>(deg, offs, bsum);
  k_scan2<<<1, 64, 0, stream>>>(bsum, boff, offs, nb);
  k_scan3<<<(NN + 255) / 256, 256, 0, stream>>>(offs, boff, cursor);
  k_scatter<<<(NE + 255) / 256, 256, 0, stream>>>(src, dst, cursor, csr_src, posmap);

  for (int l = 0; l < NL; ++l) {
    k_compute_v<<<1, 256, 0, stream>>>(edge_w + (size_t)l * DD * DD,
                                       att_edge + (size_t)l * NH * NC, vbuf);
    k_xh<<<NN / 4, 256, 0, stream>>>(nf, conv_w + (size_t)l * DD * DD,
                                     att_src + (size_t)l * NH * NC,
                                     att_dst + (size_t)l * NH * NC, xh16, asrc, adst);
    k_pass1<<<NE / 64, 256, 0, stream>>>(ef, src, dst, vbuf, asrc, adst, posmap, araw);
    k_gather<<<NN / 4, 256, 0, stream>>>(xh16, araw, csr_src, offs, asrc, adst,
                                         conv_b + (size_t)l * DD,
                                         ln_g + (size_t)l * DD,
                                         ln_b + (size_t)l * DD, nf, nf16);
    k_edge_mlp6<<<NE / EB, 512, 0, stream>>>(
        nf16, ef, src, dst,
        W1H + (size_t)l * 36864, up1_b + (size_t)l * DIN,
        up_ln_g + (size_t)l * DIN, up_ln_b + (size_t)l * DIN,
        W2H + (size_t)l * 12288, up2_b + (size_t)l * DD);
  }
}